// Round 1
// baseline (330.013 us; speedup 1.0000x reference)
//
#include <hip/hip_runtime.h>
#include <hip/hip_bf16.h>
#include <math.h>

typedef __attribute__((ext_vector_type(8))) __bf16 bf16x8;
typedef __attribute__((ext_vector_type(4))) __bf16 bf16x4;
typedef __attribute__((ext_vector_type(4))) float f32x4;

static constexpr int T_SEQ = 4096;
static constexpr int DM    = 1024;
static constexpr int NH    = 16;

// ---------------- fp32 -> bf16 convert (vectorized) ----------------
__global__ __launch_bounds__(256)
void cvt_bf16(const float* __restrict__ in, __bf16* __restrict__ out, int n4) {
    int i = blockIdx.x * blockDim.x + threadIdx.x;
    if (i >= n4) return;
    float4 v = ((const float4*)in)[i];
    bf16x4 o;
    o[0] = (__bf16)v.x; o[1] = (__bf16)v.y; o[2] = (__bf16)v.z; o[3] = (__bf16)v.w;
    ((bf16x4*)out)[i] = o;
}

// ---------------- C = A @ B^T  (A: MxK, B: NxK, both bf16 row-major) ----------------
// 128x128 tile, BK=64, 256 threads = 4 waves in 2x2, each wave 64x64 via 4x4 of 16x16x32 MFMA.
template<bool OUT_BF16>
__global__ __launch_bounds__(256)
void gemm_bt(const __bf16* __restrict__ A, const __bf16* __restrict__ B,
             void* __restrict__ Cout, int M, int N, int K, float scale)
{
    __shared__ __bf16 Alds[128][72];   // stride 144B (mult of 16B)
    __shared__ __bf16 Blds[128][72];
    const int tid  = threadIdx.x;
    const int lane = tid & 63;
    const int wid  = tid >> 6;
    const int wr   = wid >> 1, wc = wid & 1;
    const int m0   = blockIdx.y * 128, n0 = blockIdx.x * 128;
    const int r    = lane & 15, g = lane >> 4;

    f32x4 acc[4][4];
    const f32x4 z4 = {0.f, 0.f, 0.f, 0.f};
    #pragma unroll
    for (int i = 0; i < 4; ++i)
        #pragma unroll
        for (int j = 0; j < 4; ++j) acc[i][j] = z4;

    for (int kt = 0; kt < K; kt += 64) {
        __syncthreads();
        #pragma unroll
        for (int i = 0; i < 4; ++i) {
            int c    = i * 256 + tid;       // 0..1023
            int row  = c >> 3;
            int col8 = (c & 7) * 8;
            *(bf16x8*)&Alds[row][col8] = *(const bf16x8*)(A + (size_t)(m0 + row) * K + kt + col8);
            *(bf16x8*)&Blds[row][col8] = *(const bf16x8*)(B + (size_t)(n0 + row) * K + kt + col8);
        }
        __syncthreads();
        #pragma unroll
        for (int kk = 0; kk < 2; ++kk) {
            bf16x8 af[4], bfr[4];
            #pragma unroll
            for (int mi = 0; mi < 4; ++mi)
                af[mi] = *(const bf16x8*)&Alds[wr * 64 + mi * 16 + r][kk * 32 + g * 8];
            #pragma unroll
            for (int nj = 0; nj < 4; ++nj)
                bfr[nj] = *(const bf16x8*)&Blds[wc * 64 + nj * 16 + r][kk * 32 + g * 8];
            #pragma unroll
            for (int mi = 0; mi < 4; ++mi)
                #pragma unroll
                for (int nj = 0; nj < 4; ++nj)
                    acc[mi][nj] = __builtin_amdgcn_mfma_f32_16x16x32_bf16(af[mi], bfr[nj], acc[mi][nj], 0, 0, 0);
        }
    }
    #pragma unroll
    for (int mi = 0; mi < 4; ++mi)
        #pragma unroll
        for (int nj = 0; nj < 4; ++nj)
            #pragma unroll
            for (int j = 0; j < 4; ++j) {
                int row = m0 + wr * 64 + mi * 16 + g * 4 + j;
                int col = n0 + wc * 64 + nj * 16 + r;
                float v = acc[mi][nj][j] * scale;
                if (OUT_BF16) ((__bf16*)Cout)[(size_t)row * N + col] = (__bf16)v;
                else          ((float*)Cout)[(size_t)row * N + col]  = v;
            }
}

// ---------------- causal flash attention ----------------
// grid (T/64, H); 256 threads = 4 waves, each wave owns 16 q-rows.
// Q pre-scaled by 1/sqrt(dk) in its projection epilogue.
__global__ __launch_bounds__(256)
void attn_fwd(const __bf16* __restrict__ Q, const __bf16* __restrict__ Kp,
              const __bf16* __restrict__ V, __bf16* __restrict__ O)
{
    __shared__ __bf16 Klds[64][72];      // [kv][dk]
    __shared__ __bf16 Vt[64][72];        // [dk][kv]  (transposed V)
    __shared__ __bf16 Plds[4][16][72];   // per-wave P round-trip buffer
    const int tid  = threadIdx.x;
    const int lane = tid & 63, wid = tid >> 6;
    const int r    = lane & 15, g = lane >> 4;
    const int h    = blockIdx.y;
    const int qb   = gridDim.x - 1 - blockIdx.x;   // heavy blocks first
    const int qbase = qb * 64 + wid * 16;

    bf16x8 qf[2];
    #pragma unroll
    for (int kk = 0; kk < 2; ++kk)
        qf[kk] = *(const bf16x8*)(Q + (size_t)(qbase + r) * DM + h * 64 + kk * 32 + g * 8);

    float m_i[4], l_i[4];
    f32x4 oacc[4];
    const f32x4 z4 = {0.f, 0.f, 0.f, 0.f};
    #pragma unroll
    for (int j = 0; j < 4; ++j) { m_i[j] = -1e30f; l_i[j] = 0.f; }
    #pragma unroll
    for (int df = 0; df < 4; ++df) oacc[df] = z4;

    for (int kvb = 0; kvb <= qb; ++kvb) {
        __syncthreads();
        // stage K (row-major) and V^T (rotated scalar writes to spread banks)
        #pragma unroll
        for (int i = 0; i < 2; ++i) {
            int c     = i * 256 + tid;   // 0..511
            int kvrow = c >> 3;
            int col8  = c & 7;
            *(bf16x8*)&Klds[kvrow][col8 * 8] =
                *(const bf16x8*)(Kp + (size_t)(kvb * 64 + kvrow) * DM + h * 64 + col8 * 8);
            bf16x8 vv = *(const bf16x8*)(V + (size_t)(kvb * 64 + kvrow) * DM + h * 64 + col8 * 8);
            // rotate-left by col8 so t[s] has compile-time index, addresses rotate
            bf16x8 t = vv;
            t = (col8 & 1) ? __builtin_shufflevector(t, t, 1, 2, 3, 4, 5, 6, 7, 0) : t;
            t = (col8 & 2) ? __builtin_shufflevector(t, t, 2, 3, 4, 5, 6, 7, 0, 1) : t;
            t = (col8 & 4) ? __builtin_shufflevector(t, t, 4, 5, 6, 7, 0, 1, 2, 3) : t;
            #pragma unroll
            for (int s = 0; s < 8; ++s) {
                int e = (s + col8) & 7;
                Vt[col8 * 8 + e][kvrow] = t[s];
            }
        }
        __syncthreads();

        // S = Q K^T (scaled already)
        f32x4 sf[4];
        #pragma unroll
        for (int f = 0; f < 4; ++f) {
            sf[f] = z4;
            #pragma unroll
            for (int kk = 0; kk < 2; ++kk) {
                bf16x8 kf = *(const bf16x8*)&Klds[f * 16 + r][kk * 32 + g * 8];
                sf[f] = __builtin_amdgcn_mfma_f32_16x16x32_bf16(qf[kk], kf, sf[f], 0, 0, 0);
            }
        }
        // causal mask (only needed on diagonal block)
        if (kvb == qb) {
            #pragma unroll
            for (int f = 0; f < 4; ++f)
                #pragma unroll
                for (int j = 0; j < 4; ++j)
                    if (f * 16 + r > wid * 16 + g * 4 + j) sf[f][j] = -1e30f;
        }
        // online softmax (per lane: 4 q-rows; reduce across 16-lane group)
        float rowmax[4];
        #pragma unroll
        for (int j = 0; j < 4; ++j) {
            float v = sf[0][j];
            v = fmaxf(v, sf[1][j]); v = fmaxf(v, sf[2][j]); v = fmaxf(v, sf[3][j]);
            #pragma unroll
            for (int d = 1; d < 16; d <<= 1) v = fmaxf(v, __shfl_xor(v, d));
            rowmax[j] = v;
        }
        #pragma unroll
        for (int j = 0; j < 4; ++j) {
            float mn = fmaxf(m_i[j], rowmax[j]);
            float al = __expf(m_i[j] - mn);
            m_i[j] = mn;
            l_i[j] *= al;
            #pragma unroll
            for (int df = 0; df < 4; ++df) oacc[df][j] *= al;
        }
        float rowsum[4] = {0.f, 0.f, 0.f, 0.f};
        #pragma unroll
        for (int f = 0; f < 4; ++f)
            #pragma unroll
            for (int j = 0; j < 4; ++j) {
                float p = __expf(sf[f][j] - m_i[j]);
                rowsum[j] += p;
                Plds[wid][g * 4 + j][f * 16 + r] = (__bf16)p;
            }
        #pragma unroll
        for (int j = 0; j < 4; ++j) {
            float v = rowsum[j];
            #pragma unroll
            for (int d = 1; d < 16; d <<= 1) v += __shfl_xor(v, d);
            l_i[j] += v;
        }
        // O += P @ V
        #pragma unroll
        for (int kk = 0; kk < 2; ++kk) {
            bf16x8 pa = *(const bf16x8*)&Plds[wid][r][kk * 32 + g * 8];
            #pragma unroll
            for (int df = 0; df < 4; ++df) {
                bf16x8 vb = *(const bf16x8*)&Vt[df * 16 + r][kk * 32 + g * 8];
                oacc[df] = __builtin_amdgcn_mfma_f32_16x16x32_bf16(pa, vb, oacc[df], 0, 0, 0);
            }
        }
    }
    // epilogue: normalize and store
    #pragma unroll
    for (int df = 0; df < 4; ++df)
        #pragma unroll
        for (int j = 0; j < 4; ++j) {
            float v = oacc[df][j] / l_i[j];
            O[(size_t)(qbase + g * 4 + j) * DM + h * 64 + df * 16 + r] = (__bf16)v;
        }
}

extern "C" void kernel_launch(void* const* d_in, const int* in_sizes, int n_in,
                              void* d_out, int out_size, void* d_ws, size_t ws_size,
                              hipStream_t stream) {
    const float* x  = (const float*)d_in[0];
    const float* Wq = (const float*)d_in[1];
    const float* Wk = (const float*)d_in[2];
    const float* Wv = (const float*)d_in[3];
    const float* Wo = (const float*)d_in[4];
    float* out = (float*)d_out;

    char* ws = (char*)d_ws;
    const size_t MB = (size_t)1 << 20;
    __bf16* xb    = (__bf16*)(ws + 0 * MB);    // 8 MiB
    __bf16* wqb   = (__bf16*)(ws + 8 * MB);    // 2 MiB
    __bf16* wkb   = (__bf16*)(ws + 10 * MB);
    __bf16* wvb   = (__bf16*)(ws + 12 * MB);
    __bf16* wob   = (__bf16*)(ws + 14 * MB);
    __bf16* Qb    = (__bf16*)(ws + 16 * MB);   // 8 MiB each
    __bf16* Kb    = (__bf16*)(ws + 24 * MB);
    __bf16* Vb    = (__bf16*)(ws + 32 * MB);
    __bf16* attnb = (__bf16*)(ws + 40 * MB);   // end at 48 MiB

    const int nX = T_SEQ * DM / 4;   // float4 chunks
    const int nW = DM * DM / 4;
    cvt_bf16<<<(nX + 255) / 256, 256, 0, stream>>>(x,  xb,  nX);
    cvt_bf16<<<(nW + 255) / 256, 256, 0, stream>>>(Wq, wqb, nW);
    cvt_bf16<<<(nW + 255) / 256, 256, 0, stream>>>(Wk, wkb, nW);
    cvt_bf16<<<(nW + 255) / 256, 256, 0, stream>>>(Wv, wvb, nW);
    cvt_bf16<<<(nW + 255) / 256, 256, 0, stream>>>(Wo, wob, nW);

    dim3 gg(DM / 128, T_SEQ / 128);   // (8, 32)
    gemm_bt<true><<<gg, 256, 0, stream>>>(xb, wqb, Qb, T_SEQ, DM, DM, 0.125f);  // Q pre-scaled
    gemm_bt<true><<<gg, 256, 0, stream>>>(xb, wkb, Kb, T_SEQ, DM, DM, 1.0f);
    gemm_bt<true><<<gg, 256, 0, stream>>>(xb, wvb, Vb, T_SEQ, DM, DM, 1.0f);

    dim3 ga(T_SEQ / 64, NH);          // (64, 16)
    attn_fwd<<<ga, 256, 0, stream>>>(Qb, Kb, Vb, attnb);

    gemm_bt<false><<<gg, 256, 0, stream>>>(attnb, wob, out, T_SEQ, DM, DM, 1.0f);
}

// Round 2
// 314.560 us; speedup vs baseline: 1.0491x; 1.0491x over previous
//
#include <hip/hip_runtime.h>
#include <hip/hip_bf16.h>
#include <math.h>

typedef __attribute__((ext_vector_type(8))) __bf16 bf16x8;
typedef __attribute__((ext_vector_type(4))) __bf16 bf16x4;
typedef __attribute__((ext_vector_type(4))) float f32x4;

static constexpr int T_SEQ = 4096;
static constexpr int DM    = 1024;
static constexpr int NH    = 16;
// 1/sqrt(dk) * log2(e): softmax done in exp2 domain
static constexpr float QSCALE = 0.125f * 1.44269504088896340736f;

__device__ __forceinline__ void gload16(const void* g, void* l) {
    __builtin_amdgcn_global_load_lds(
        (const __attribute__((address_space(1))) unsigned int*)g,
        (__attribute__((address_space(3))) unsigned int*)l,
        16, 0, 0);
}

// ---------------- fp32 -> bf16 converts ----------------
__global__ __launch_bounds__(256)
void cvt_bf16(const float* __restrict__ in, __bf16* __restrict__ out, int n4) {
    int i = blockIdx.x * blockDim.x + threadIdx.x;
    if (i >= n4) return;
    float4 v = ((const float4*)in)[i];
    bf16x4 o;
    o[0] = (__bf16)v.x; o[1] = (__bf16)v.y; o[2] = (__bf16)v.z; o[3] = (__bf16)v.w;
    ((bf16x4*)out)[i] = o;
}

__global__ __launch_bounds__(256)
void cvt4_bf16(const float* __restrict__ a0, const float* __restrict__ a1,
               const float* __restrict__ a2, const float* __restrict__ a3,
               __bf16* __restrict__ o0, __bf16* __restrict__ o1,
               __bf16* __restrict__ o2, __bf16* __restrict__ o3, int n4) {
    int i = blockIdx.x * blockDim.x + threadIdx.x;
    if (i >= n4) return;
    const float* in = blockIdx.y == 0 ? a0 : blockIdx.y == 1 ? a1 : blockIdx.y == 2 ? a2 : a3;
    __bf16* out     = blockIdx.y == 0 ? o0 : blockIdx.y == 1 ? o1 : blockIdx.y == 2 ? o2 : o3;
    float4 v = ((const float4*)in)[i];
    bf16x4 o;
    o[0] = (__bf16)v.x; o[1] = (__bf16)v.y; o[2] = (__bf16)v.z; o[3] = (__bf16)v.w;
    ((bf16x4*)out)[i] = o;
}

// ---------------- GEMM body: C = A @ B^T (m97 structure: gload_lds + XOR swizzle) ----
// 128x128 tile, BK=64, 4 waves 2x2, wave 64x64 via 4x4 MFMA 16x16x32.
template<bool OUT_BF16>
__device__ __forceinline__ void gemm_body(const __bf16* __restrict__ A,
                                          const __bf16* __restrict__ B,
                                          void* __restrict__ Cout,
                                          int N, int K, float scale,
                                          int bx, int by) {
    __shared__ __align__(16) __bf16 Al[128 * 64];
    __shared__ __align__(16) __bf16 Bl[128 * 64];
    const int tid  = threadIdx.x;
    const int lane = tid & 63;
    const int wid  = tid >> 6;
    const int wr   = wid >> 1, wc = wid & 1;
    const int m0   = by * 128, n0 = bx * 128;
    const int r    = lane & 15, g = lane >> 4;

    f32x4 acc[4][4];
    const f32x4 z4 = {0.f, 0.f, 0.f, 0.f};
    #pragma unroll
    for (int i = 0; i < 4; ++i)
        #pragma unroll
        for (int j = 0; j < 4; ++j) acc[i][j] = z4;

    for (int kt = 0; kt < K; kt += 64) {
        __syncthreads();
        #pragma unroll
        for (int p = 0; p < 4; ++p) {
            int u    = p * 256 + tid;          // 16B unit index, 0..1023
            int row  = u >> 3;
            int col8 = (u & 7) ^ (row & 7);    // inverse-swizzled global source
            gload16(A + (size_t)(m0 + row) * K + kt + col8 * 8,
                    (char*)Al + (p * 256 + wid * 64) * 16);
            gload16(B + (size_t)(n0 + row) * K + kt + col8 * 8,
                    (char*)Bl + (p * 256 + wid * 64) * 16);
        }
        __syncthreads();
        __builtin_amdgcn_s_setprio(1);
        #pragma unroll
        for (int kk = 0; kk < 2; ++kk) {
            bf16x8 af[4], bfr[4];
            #pragma unroll
            for (int mi = 0; mi < 4; ++mi)
                af[mi] = *(const bf16x8*)&Al[(wr * 64 + mi * 16 + r) * 64 + (((kk * 4 + g) ^ (r & 7)) * 8)];
            #pragma unroll
            for (int nj = 0; nj < 4; ++nj)
                bfr[nj] = *(const bf16x8*)&Bl[(wc * 64 + nj * 16 + r) * 64 + (((kk * 4 + g) ^ (r & 7)) * 8)];
            #pragma unroll
            for (int mi = 0; mi < 4; ++mi)
                #pragma unroll
                for (int nj = 0; nj < 4; ++nj)
                    acc[mi][nj] = __builtin_amdgcn_mfma_f32_16x16x32_bf16(af[mi], bfr[nj], acc[mi][nj], 0, 0, 0);
        }
        __builtin_amdgcn_s_setprio(0);
    }
    #pragma unroll
    for (int mi = 0; mi < 4; ++mi)
        #pragma unroll
        for (int nj = 0; nj < 4; ++nj)
            #pragma unroll
            for (int j = 0; j < 4; ++j) {
                int row = m0 + wr * 64 + mi * 16 + g * 4 + j;
                int col = n0 + wc * 64 + nj * 16 + r;
                float v = acc[mi][nj][j] * scale;
                if (OUT_BF16) ((__bf16*)Cout)[(size_t)row * N + col] = (__bf16)v;
                else          ((float*)Cout)[(size_t)row * N + col]  = v;
            }
}

// fused Q/K/V projections: grid (N/128, M/128, 3)
__global__ __launch_bounds__(256)
void gemm_qkv(const __bf16* __restrict__ A,
              const __bf16* __restrict__ W0, const __bf16* __restrict__ W1,
              const __bf16* __restrict__ W2,
              __bf16* __restrict__ O0, __bf16* __restrict__ O1, __bf16* __restrict__ O2) {
    const int z = blockIdx.z;
    const __bf16* B = z == 0 ? W0 : (z == 1 ? W1 : W2);
    __bf16*       C = z == 0 ? O0 : (z == 1 ? O1 : O2);
    float scale = z == 0 ? QSCALE : 1.0f;
    gemm_body<true>(A, B, C, DM, DM, scale, blockIdx.x, blockIdx.y);
}

__global__ __launch_bounds__(256)
void gemm_out(const __bf16* __restrict__ A, const __bf16* __restrict__ B,
              float* __restrict__ C) {
    gemm_body<false>(A, B, C, DM, DM, 1.0f, blockIdx.x, blockIdx.y);
}

// ---------------- V transpose: Vt[h*64+d][t] = V[t][h*64+d] ----------------
__global__ __launch_bounds__(256)
void vtrans(const __bf16* __restrict__ V, __bf16* __restrict__ Vt) {
    __shared__ __bf16 tl[64][72];
    const int tid = threadIdx.x;
    const int t0  = blockIdx.x * 64;
    const int h   = blockIdx.y;
    #pragma unroll
    for (int p = 0; p < 2; ++p) {
        int c = p * 256 + tid, row = c >> 3, col8 = c & 7;
        *(bf16x8*)&tl[row][col8 * 8] =
            *(const bf16x8*)(V + (size_t)(t0 + row) * DM + h * 64 + col8 * 8);
    }
    __syncthreads();
    #pragma unroll
    for (int p = 0; p < 2; ++p) {
        int c = p * 256 + tid, d = c >> 3, tc8 = c & 7;
        bf16x8 o;
        #pragma unroll
        for (int e = 0; e < 8; ++e) o[e] = tl[tc8 * 8 + e][d];
        *(bf16x8*)(Vt + (size_t)(h * 64 + d) * T_SEQ + t0 + tc8 * 8) = o;
    }
}

// ---------------- causal flash attention v2 ----------------
// grid (T/128, H); 256 threads = 4 waves, each wave owns 32 q-rows (2x16 frags).
// K, V^T double-buffered in swizzled [64][64] LDS via global_load_lds.
__global__ __launch_bounds__(256)
void attn_fwd(const __bf16* __restrict__ Q, const __bf16* __restrict__ Kp,
              const __bf16* __restrict__ Vt, __bf16* __restrict__ O)
{
    __shared__ __align__(16) __bf16 Kl[2][64 * 64];
    __shared__ __align__(16) __bf16 Vl[2][64 * 64];
    __shared__ __align__(16) __bf16 Pl[4][32 * 64];
    const int tid  = threadIdx.x;
    const int lane = tid & 63, wid = tid >> 6;
    const int r    = lane & 15, g = lane >> 4;
    const int h    = blockIdx.y;
    const int qb   = gridDim.x - 1 - blockIdx.x;   // heavy blocks first
    const int qw   = qb * 128 + wid * 32;          // this wave's first q row

    bf16x8 qf[2][2];
    #pragma unroll
    for (int qr = 0; qr < 2; ++qr)
        #pragma unroll
        for (int kk = 0; kk < 2; ++kk)
            qf[qr][kk] = *(const bf16x8*)(Q + (size_t)(qw + qr * 16 + r) * DM + h * 64 + kk * 32 + g * 8);

    float m_i[2][4], l_i[2][4];
    f32x4 oacc[2][4];
    const f32x4 z4 = {0.f, 0.f, 0.f, 0.f};
    #pragma unroll
    for (int qr = 0; qr < 2; ++qr)
        #pragma unroll
        for (int j = 0; j < 4; ++j) { m_i[qr][j] = -1e30f; l_i[qr][j] = 0.f; }
    #pragma unroll
    for (int qr = 0; qr < 2; ++qr)
        #pragma unroll
        for (int df = 0; df < 4; ++df) oacc[qr][df] = z4;

    const int nt = 2 * qb + 2;

    auto stage = [&](int t, int buf) {
        #pragma unroll
        for (int p = 0; p < 2; ++p) {
            int u    = p * 256 + tid;          // 16B unit, 0..511
            int row  = u >> 3;
            int col8 = (u & 7) ^ (row & 7);
            gload16(Kp + (size_t)(t * 64 + row) * DM + h * 64 + col8 * 8,
                    (char*)&Kl[buf][0] + (p * 256 + wid * 64) * 16);
            gload16(Vt + (size_t)(h * 64 + row) * T_SEQ + t * 64 + col8 * 8,
                    (char*)&Vl[buf][0] + (p * 256 + wid * 64) * 16);
        }
    };

    stage(0, 0);
    int cur = 0;
    for (int t = 0; t < nt; ++t) {
        __syncthreads();                    // buf[cur] staged; prev compute done
        if (t + 1 < nt) stage(t + 1, cur ^ 1);
        if (t * 64 <= qw + 31) {            // wave has unmasked work in this tile
            // ---- S = Q K^T ----
            f32x4 sf[2][4];
            #pragma unroll
            for (int qr = 0; qr < 2; ++qr)
                #pragma unroll
                for (int f = 0; f < 4; ++f) sf[qr][f] = z4;
            __builtin_amdgcn_s_setprio(1);
            #pragma unroll
            for (int f = 0; f < 4; ++f)
                #pragma unroll
                for (int kk = 0; kk < 2; ++kk) {
                    bf16x8 kf = *(const bf16x8*)&Kl[cur][(f * 16 + r) * 64 + (((kk * 4 + g) ^ (r & 7)) * 8)];
                    sf[0][f] = __builtin_amdgcn_mfma_f32_16x16x32_bf16(qf[0][kk], kf, sf[0][f], 0, 0, 0);
                    sf[1][f] = __builtin_amdgcn_mfma_f32_16x16x32_bf16(qf[1][kk], kf, sf[1][f], 0, 0, 0);
                }
            __builtin_amdgcn_s_setprio(0);
            // ---- causal mask (only near diagonal) ----
            if (t * 64 + 63 > qw) {
                #pragma unroll
                for (int qr = 0; qr < 2; ++qr)
                    #pragma unroll
                    for (int f = 0; f < 4; ++f)
                        #pragma unroll
                        for (int j = 0; j < 4; ++j) {
                            int rowq = qw + qr * 16 + g * 4 + j;
                            int colk = t * 64 + f * 16 + r;
                            if (colk > rowq) sf[qr][f][j] = -1e30f;
                        }
            }
            // ---- online softmax (exp2 domain), P -> swizzled LDS ----
            #pragma unroll
            for (int qr = 0; qr < 2; ++qr)
                #pragma unroll
                for (int j = 0; j < 4; ++j) {
                    float v = fmaxf(fmaxf(sf[qr][0][j], sf[qr][1][j]),
                                    fmaxf(sf[qr][2][j], sf[qr][3][j]));
                    v = fmaxf(v, __shfl_xor(v, 1));
                    v = fmaxf(v, __shfl_xor(v, 2));
                    v = fmaxf(v, __shfl_xor(v, 4));
                    v = fmaxf(v, __shfl_xor(v, 8));
                    float mo = m_i[qr][j];
                    float mn = fmaxf(mo, v);
                    float al = exp2f(mo - mn);
                    m_i[qr][j] = mn;
                    l_i[qr][j] *= al;
                    #pragma unroll
                    for (int df = 0; df < 4; ++df) oacc[qr][df][j] *= al;
                    float rs = 0.f;
                    const int prow = qr * 16 + g * 4 + j;
                    #pragma unroll
                    for (int f = 0; f < 4; ++f) {
                        float p = exp2f(sf[qr][f][j] - mn);
                        rs += p;
                        int pcol = f * 16 + r;
                        Pl[wid][prow * 64 + (pcol ^ ((prow & 7) << 3))] = (__bf16)p;
                    }
                    rs += __shfl_xor(rs, 1);
                    rs += __shfl_xor(rs, 2);
                    rs += __shfl_xor(rs, 4);
                    rs += __shfl_xor(rs, 8);
                    l_i[qr][j] += rs;
                }
            // ---- O += P @ V ----
            __builtin_amdgcn_s_setprio(1);
            #pragma unroll
            for (int kk = 0; kk < 2; ++kk) {
                bf16x8 pa[2];
                #pragma unroll
                for (int qr = 0; qr < 2; ++qr)
                    pa[qr] = *(const bf16x8*)&Pl[wid][(qr * 16 + r) * 64 + (((kk * 4 + g) ^ (r & 7)) * 8)];
                #pragma unroll
                for (int df = 0; df < 4; ++df) {
                    bf16x8 vb = *(const bf16x8*)&Vl[cur][(df * 16 + r) * 64 + (((kk * 4 + g) ^ (r & 7)) * 8)];
                    oacc[0][df] = __builtin_amdgcn_mfma_f32_16x16x32_bf16(pa[0], vb, oacc[0][df], 0, 0, 0);
                    oacc[1][df] = __builtin_amdgcn_mfma_f32_16x16x32_bf16(pa[1], vb, oacc[1][df], 0, 0, 0);
                }
            }
            __builtin_amdgcn_s_setprio(0);
        }
        cur ^= 1;
    }
    // ---- epilogue ----
    #pragma unroll
    for (int qr = 0; qr < 2; ++qr)
        #pragma unroll
        for (int j = 0; j < 4; ++j) {
            float inv = 1.f / l_i[qr][j];
            #pragma unroll
            for (int df = 0; df < 4; ++df) {
                float v = oacc[qr][df][j] * inv;
                O[(size_t)(qw + qr * 16 + g * 4 + j) * DM + h * 64 + df * 16 + r] = (__bf16)v;
            }
        }
}

extern "C" void kernel_launch(void* const* d_in, const int* in_sizes, int n_in,
                              void* d_out, int out_size, void* d_ws, size_t ws_size,
                              hipStream_t stream) {
    const float* x  = (const float*)d_in[0];
    const float* Wq = (const float*)d_in[1];
    const float* Wk = (const float*)d_in[2];
    const float* Wv = (const float*)d_in[3];
    const float* Wo = (const float*)d_in[4];
    float* out = (float*)d_out;

    char* ws = (char*)d_ws;
    const size_t MB = (size_t)1 << 20;
    __bf16* xb    = (__bf16*)(ws + 0 * MB);    // 8 MiB (dead after QKV gemms)
    __bf16* VtG   = (__bf16*)(ws + 0 * MB);    // reuses xb region
    __bf16* wqb   = (__bf16*)(ws + 8 * MB);
    __bf16* wkb   = (__bf16*)(ws + 10 * MB);
    __bf16* wvb   = (__bf16*)(ws + 12 * MB);
    __bf16* wob   = (__bf16*)(ws + 14 * MB);
    __bf16* Qb    = (__bf16*)(ws + 16 * MB);
    __bf16* Kb    = (__bf16*)(ws + 24 * MB);
    __bf16* Vb    = (__bf16*)(ws + 32 * MB);
    __bf16* attnb = (__bf16*)(ws + 40 * MB);   // ends at 48 MiB

    const int nX = T_SEQ * DM / 4;
    const int nW = DM * DM / 4;
    cvt_bf16<<<(nX + 255) / 256, 256, 0, stream>>>(x, xb, nX);
    cvt4_bf16<<<dim3((nW + 255) / 256, 4), 256, 0, stream>>>(Wq, Wk, Wv, Wo,
                                                             wqb, wkb, wvb, wob, nW);

    gemm_qkv<<<dim3(DM / 128, T_SEQ / 128, 3), 256, 0, stream>>>(xb, wqb, wkb, wvb, Qb, Kb, Vb);

    vtrans<<<dim3(T_SEQ / 64, NH), 256, 0, stream>>>(Vb, VtG);

    attn_fwd<<<dim3(T_SEQ / 128, NH), 256, 0, stream>>>(Qb, Kb, VtG, attnb);

    gemm_out<<<dim3(DM / 128, T_SEQ / 128), 256, 0, stream>>>(attnb, wob, out);
}

// Round 3
// 224.196 us; speedup vs baseline: 1.4720x; 1.4031x over previous
//
#include <hip/hip_runtime.h>
#include <hip/hip_bf16.h>
#include <math.h>

typedef __attribute__((ext_vector_type(8)))  __bf16 bf16x8;
typedef __attribute__((ext_vector_type(4)))  __bf16 bf16x4;
typedef __attribute__((ext_vector_type(4)))  float  f32x4;
typedef __attribute__((ext_vector_type(16))) float  f32x16;

static constexpr int T_SEQ = 4096;
static constexpr int DM    = 1024;
static constexpr int NH    = 16;
// 1/sqrt(dk) * log2(e): softmax done in exp2 domain
static constexpr float QSCALE = 0.125f * 1.44269504088896340736f;

__device__ __forceinline__ void gload16(const void* g, void* l) {
    __builtin_amdgcn_global_load_lds(
        (const __attribute__((address_space(1))) unsigned int*)g,
        (__attribute__((address_space(3))) unsigned int*)l,
        16, 0, 0);
}

__device__ __forceinline__ unsigned cvtpk_bf16(float a, float b) {
    unsigned r;
    asm("v_cvt_pk_bf16_f32 %0, %1, %2" : "=v"(r) : "v"(a), "v"(b));
    return r;
}
// v_permlane32_swap_b32: vdst[32+i] <-> src[i]  (both results used)
__device__ __forceinline__ void permswap(unsigned& x, unsigned& y) {
    asm("v_permlane32_swap_b32 %0, %1" : "+v"(x), "+v"(y));
}

// ---------------- fp32 -> bf16 converts ----------------
__global__ __launch_bounds__(256)
void cvt_bf16(const float* __restrict__ in, __bf16* __restrict__ out, int n4) {
    int i = blockIdx.x * blockDim.x + threadIdx.x;
    if (i >= n4) return;
    float4 v = ((const float4*)in)[i];
    bf16x4 o;
    o[0] = (__bf16)v.x; o[1] = (__bf16)v.y; o[2] = (__bf16)v.z; o[3] = (__bf16)v.w;
    ((bf16x4*)out)[i] = o;
}

__global__ __launch_bounds__(256)
void cvt4_bf16(const float* __restrict__ a0, const float* __restrict__ a1,
               const float* __restrict__ a2, const float* __restrict__ a3,
               __bf16* __restrict__ o0, __bf16* __restrict__ o1,
               __bf16* __restrict__ o2, __bf16* __restrict__ o3, int n4) {
    int i = blockIdx.x * blockDim.x + threadIdx.x;
    if (i >= n4) return;
    const float* in = blockIdx.y == 0 ? a0 : blockIdx.y == 1 ? a1 : blockIdx.y == 2 ? a2 : a3;
    __bf16* out     = blockIdx.y == 0 ? o0 : blockIdx.y == 1 ? o1 : blockIdx.y == 2 ? o2 : o3;
    float4 v = ((const float4*)in)[i];
    bf16x4 o;
    o[0] = (__bf16)v.x; o[1] = (__bf16)v.y; o[2] = (__bf16)v.z; o[3] = (__bf16)v.w;
    ((bf16x4*)out)[i] = o;
}

// ---------------- GEMM body: C = A @ B^T (m97 structure) ----------------
template<bool OUT_BF16>
__device__ __forceinline__ void gemm_body(const __bf16* __restrict__ A,
                                          const __bf16* __restrict__ B,
                                          void* __restrict__ Cout,
                                          int N, int K, float scale,
                                          int bx, int by) {
    __shared__ __align__(16) __bf16 Al[128 * 64];
    __shared__ __align__(16) __bf16 Bl[128 * 64];
    const int tid  = threadIdx.x;
    const int lane = tid & 63;
    const int wid  = tid >> 6;
    const int wr   = wid >> 1, wc = wid & 1;
    const int m0   = by * 128, n0 = bx * 128;
    const int r    = lane & 15, g = lane >> 4;

    f32x4 acc[4][4];
    const f32x4 z4 = {0.f, 0.f, 0.f, 0.f};
    #pragma unroll
    for (int i = 0; i < 4; ++i)
        #pragma unroll
        for (int j = 0; j < 4; ++j) acc[i][j] = z4;

    for (int kt = 0; kt < K; kt += 64) {
        __syncthreads();
        #pragma unroll
        for (int p = 0; p < 4; ++p) {
            int u    = p * 256 + tid;
            int row  = u >> 3;
            int col8 = (u & 7) ^ (row & 7);
            gload16(A + (size_t)(m0 + row) * K + kt + col8 * 8,
                    (char*)Al + (p * 256 + wid * 64) * 16);
            gload16(B + (size_t)(n0 + row) * K + kt + col8 * 8,
                    (char*)Bl + (p * 256 + wid * 64) * 16);
        }
        __syncthreads();
        __builtin_amdgcn_s_setprio(1);
        #pragma unroll
        for (int kk = 0; kk < 2; ++kk) {
            bf16x8 af[4], bfr[4];
            #pragma unroll
            for (int mi = 0; mi < 4; ++mi)
                af[mi] = *(const bf16x8*)&Al[(wr * 64 + mi * 16 + r) * 64 + (((kk * 4 + g) ^ (r & 7)) * 8)];
            #pragma unroll
            for (int nj = 0; nj < 4; ++nj)
                bfr[nj] = *(const bf16x8*)&Bl[(wc * 64 + nj * 16 + r) * 64 + (((kk * 4 + g) ^ (r & 7)) * 8)];
            #pragma unroll
            for (int mi = 0; mi < 4; ++mi)
                #pragma unroll
                for (int nj = 0; nj < 4; ++nj)
                    acc[mi][nj] = __builtin_amdgcn_mfma_f32_16x16x32_bf16(af[mi], bfr[nj], acc[mi][nj], 0, 0, 0);
        }
        __builtin_amdgcn_s_setprio(0);
    }
    #pragma unroll
    for (int mi = 0; mi < 4; ++mi)
        #pragma unroll
        for (int nj = 0; nj < 4; ++nj)
            #pragma unroll
            for (int j = 0; j < 4; ++j) {
                int row = m0 + wr * 64 + mi * 16 + g * 4 + j;
                int col = n0 + wc * 64 + nj * 16 + r;
                float v = acc[mi][nj][j] * scale;
                if (OUT_BF16) ((__bf16*)Cout)[(size_t)row * N + col] = (__bf16)v;
                else          ((float*)Cout)[(size_t)row * N + col]  = v;
            }
}

__global__ __launch_bounds__(256)
void gemm_qkv(const __bf16* __restrict__ A,
              const __bf16* __restrict__ W0, const __bf16* __restrict__ W1,
              const __bf16* __restrict__ W2,
              __bf16* __restrict__ O0, __bf16* __restrict__ O1, __bf16* __restrict__ O2) {
    const int z = blockIdx.z;
    const __bf16* B = z == 0 ? W0 : (z == 1 ? W1 : W2);
    __bf16*       C = z == 0 ? O0 : (z == 1 ? O1 : O2);
    float scale = z == 0 ? QSCALE : 1.0f;
    gemm_body<true>(A, B, C, DM, DM, scale, blockIdx.x, blockIdx.y);
}

__global__ __launch_bounds__(256)
void gemm_out(const __bf16* __restrict__ A, const __bf16* __restrict__ B,
              float* __restrict__ C) {
    gemm_body<false>(A, B, C, DM, DM, 1.0f, blockIdx.x, blockIdx.y);
}

// ---------------- V transpose: Vt[h*64+d][t] = V[t][h*64+d] ----------------
__global__ __launch_bounds__(256)
void vtrans(const __bf16* __restrict__ V, __bf16* __restrict__ Vt) {
    __shared__ __bf16 tl[64][72];
    const int tid = threadIdx.x;
    const int t0  = blockIdx.x * 64;
    const int h   = blockIdx.y;
    #pragma unroll
    for (int p = 0; p < 2; ++p) {
        int c = p * 256 + tid, row = c >> 3, col8 = c & 7;
        *(bf16x8*)&tl[row][col8 * 8] =
            *(const bf16x8*)(V + (size_t)(t0 + row) * DM + h * 64 + col8 * 8);
    }
    __syncthreads();
    #pragma unroll
    for (int p = 0; p < 2; ++p) {
        int c = p * 256 + tid, d = c >> 3, tc8 = c & 7;
        bf16x8 o;
        #pragma unroll
        for (int e = 0; e < 8; ++e) o[e] = tl[tc8 * 8 + e][d];
        *(bf16x8*)(Vt + (size_t)(h * 64 + d) * T_SEQ + t0 + tc8 * 8) = o;
    }
}

// ---------------- causal flash attention v3 ----------------
// 32x32x16 MFMA, swapped QK^T, in-register softmax, P in registers via
// cvt_pk + permlane32_swap; O accumulated transposed (q = lane&31).
// grid (T/128, H); 256 threads = 4 waves, each wave owns 32 q-rows.
__global__ __launch_bounds__(256)
void attn_fwd(const __bf16* __restrict__ Q, const __bf16* __restrict__ Kp,
              const __bf16* __restrict__ Vt, __bf16* __restrict__ O)
{
    __shared__ __align__(16) __bf16 Kl[2][64 * 64];
    __shared__ __align__(16) __bf16 Vl[2][64 * 64];
    const int tid  = threadIdx.x;
    const int lane = tid & 63, wid = tid >> 6;
    const int l31  = lane & 31;
    const int hi   = lane >> 5;
    const int h    = blockIdx.y;
    const int qb   = gridDim.x - 1 - blockIdx.x;   // heavy blocks first
    const int qw   = qb * 128 + wid * 32;          // wave's first q row
    const int qg   = qw + l31;                     // this lane's q row

    // Q fragments (B-operand): qf[kd0] = Q[qg][kd0*16 + hi*8 .. +7]
    bf16x8 qf[4];
    #pragma unroll
    for (int kd0 = 0; kd0 < 4; ++kd0)
        qf[kd0] = *(const bf16x8*)(Q + (size_t)qg * DM + h * 64 + kd0 * 16 + hi * 8);

    float m_i = -1e30f, l_i = 0.f;
    f32x16 oacc[2];
    #pragma unroll
    for (int d = 0; d < 2; ++d)
        #pragma unroll
        for (int e = 0; e < 16; ++e) oacc[d][e] = 0.f;

    const int nt = 2 * qb + 2;

    auto stage = [&](int t, int buf) {
        #pragma unroll
        for (int p = 0; p < 2; ++p) {
            int u    = p * 256 + tid;
            int row  = u >> 3;
            int col8 = (u & 7) ^ (row & 7);
            gload16(Kp + (size_t)(t * 64 + row) * DM + h * 64 + col8 * 8,
                    (char*)&Kl[buf][0] + (p * 256 + wid * 64) * 16);
            gload16(Vt + (size_t)(h * 64 + row) * T_SEQ + t * 64 + col8 * 8,
                    (char*)&Vl[buf][0] + (p * 256 + wid * 64) * 16);
        }
    };

    stage(0, 0);
    int cur = 0;
    for (int t = 0; t < nt; ++t) {
        __syncthreads();                    // buf[cur] staged; prev compute done
        if (t + 1 < nt) stage(t + 1, cur ^ 1);
        if (t * 64 <= qw + 31) {
            // ---- S^T = K Q^T : sf[ksub][reg] = S[qg][t*64+ksub*32+pat(reg)+4*hi]
            f32x16 sf[2];
            #pragma unroll
            for (int ks = 0; ks < 2; ++ks)
                #pragma unroll
                for (int e = 0; e < 16; ++e) sf[ks][e] = 0.f;
            __builtin_amdgcn_s_setprio(1);
            #pragma unroll
            for (int ksub = 0; ksub < 2; ++ksub) {
                const int row = ksub * 32 + l31;
                #pragma unroll
                for (int kd0 = 0; kd0 < 4; ++kd0) {
                    bf16x8 kf = *(const bf16x8*)
                        &Kl[cur][(row << 6) + ((((kd0 << 1) + hi) ^ (row & 7)) << 3)];
                    sf[ksub] = __builtin_amdgcn_mfma_f32_32x32x16_bf16(kf, qf[kd0], sf[ksub], 0, 0, 0);
                }
            }
            __builtin_amdgcn_s_setprio(0);
            // ---- causal mask (diagonal tiles only) ----
            if ((t << 6) + 63 > qw) {
                const int kb = (t << 6) + 4 * hi;
                #pragma unroll
                for (int ksub = 0; ksub < 2; ++ksub)
                    #pragma unroll
                    for (int e = 0; e < 16; ++e) {
                        int k = kb + ksub * 32 + ((e & 3) + 8 * (e >> 2));
                        if (k > qg) sf[ksub][e] = -1e30f;
                    }
            }
            // ---- online softmax, fully in-register ----
            float pm;
            {
                float t0[8];
                #pragma unroll
                for (int e = 0; e < 8; ++e)
                    t0[e] = fmaxf(fmaxf(sf[0][e], sf[0][e + 8]), fmaxf(sf[1][e], sf[1][e + 8]));
                #pragma unroll
                for (int s = 4; s > 0; s >>= 1)
                    #pragma unroll
                    for (int e = 0; e < s; ++e) t0[e] = fmaxf(t0[e], t0[e + s]);
                pm = t0[0];
            }
            pm = fmaxf(pm, __shfl_xor(pm, 32));
            float mn = fmaxf(m_i, pm);
            float al = exp2f(m_i - mn);
            m_i = mn;
            l_i *= al;
            #pragma unroll
            for (int d = 0; d < 2; ++d)
                #pragma unroll
                for (int e = 0; e < 16; ++e) oacc[d][e] *= al;
            float p[32];
            #pragma unroll
            for (int i = 0; i < 32; ++i)
                p[i] = exp2f(sf[i >> 4][i & 15] - mn);
            {
                float s0[8];
                #pragma unroll
                for (int e = 0; e < 8; ++e)
                    s0[e] = (p[e] + p[e + 8]) + (p[e + 16] + p[e + 24]);
                #pragma unroll
                for (int s = 4; s > 0; s >>= 1)
                    #pragma unroll
                    for (int e = 0; e < s; ++e) s0[e] += s0[e + s];
                float rs = s0[0];
                rs += __shfl_xor(rs, 32);
                l_i += rs;
            }
            // ---- P -> bf16 fragments (cvt_pk + permlane32_swap), O^T += V^T P^T
            __builtin_amdgcn_s_setprio(1);
            #pragma unroll
            for (int ks = 0; ks < 4; ++ks) {
                unsigned w0 = cvtpk_bf16(p[8 * ks + 0], p[8 * ks + 1]);
                unsigned w1 = cvtpk_bf16(p[8 * ks + 2], p[8 * ks + 3]);
                unsigned w2 = cvtpk_bf16(p[8 * ks + 4], p[8 * ks + 5]);
                unsigned w3 = cvtpk_bf16(p[8 * ks + 6], p[8 * ks + 7]);
                permswap(w0, w2);
                permswap(w1, w3);
                union { unsigned u[4]; bf16x8 v; } pu;
                pu.u[0] = w0; pu.u[1] = w1; pu.u[2] = w2; pu.u[3] = w3;
                #pragma unroll
                for (int dsub = 0; dsub < 2; ++dsub) {
                    const int row = dsub * 32 + l31;
                    bf16x8 vt = *(const bf16x8*)
                        &Vl[cur][(row << 6) + ((((ks << 1) + hi) ^ (row & 7)) << 3)];
                    oacc[dsub] = __builtin_amdgcn_mfma_f32_32x32x16_bf16(vt, pu.v, oacc[dsub], 0, 0, 0);
                }
            }
            __builtin_amdgcn_s_setprio(0);
        }
        cur ^= 1;
    }
    // ---- epilogue: normalize, transpose via per-wave LDS, coalesced store ----
    __syncthreads();
    __bf16* ow = &Kl[0][0] + wid * 2048;   // per-wave [32 q][64 d], 16B-swizzled
    const float invl = 1.f / l_i;
    #pragma unroll
    for (int dsub = 0; dsub < 2; ++dsub)
        #pragma unroll
        for (int e = 0; e < 16; ++e) {
            int d = dsub * 32 + ((e & 3) + 8 * (e >> 2)) + 4 * hi;
            float v = oacc[dsub][e] * invl;
            int bo = l31 * 128 + ((2 * d) ^ ((l31 & 7) << 4));
            *(__bf16*)((char*)ow + bo) = (__bf16)v;
        }
    #pragma unroll
    for (int i = 0; i < 4; ++i) {
        int u  = hi * 4 + i;
        int bo = l31 * 128 + ((u * 16) ^ ((l31 & 7) << 4));
        bf16x8 v8 = *(const bf16x8*)((char*)ow + bo);
        *(bf16x8*)(O + (size_t)qg * DM + h * 64 + u * 8) = v8;
    }
}

extern "C" void kernel_launch(void* const* d_in, const int* in_sizes, int n_in,
                              void* d_out, int out_size, void* d_ws, size_t ws_size,
                              hipStream_t stream) {
    const float* x  = (const float*)d_in[0];
    const float* Wq = (const float*)d_in[1];
    const float* Wk = (const float*)d_in[2];
    const float* Wv = (const float*)d_in[3];
    const float* Wo = (const float*)d_in[4];
    float* out = (float*)d_out;

    char* ws = (char*)d_ws;
    const size_t MB = (size_t)1 << 20;
    __bf16* xb    = (__bf16*)(ws + 0 * MB);    // 8 MiB (dead after QKV gemms)
    __bf16* VtG   = (__bf16*)(ws + 0 * MB);    // reuses xb region
    __bf16* wqb   = (__bf16*)(ws + 8 * MB);
    __bf16* wkb   = (__bf16*)(ws + 10 * MB);
    __bf16* wvb   = (__bf16*)(ws + 12 * MB);
    __bf16* wob   = (__bf16*)(ws + 14 * MB);
    __bf16* Qb    = (__bf16*)(ws + 16 * MB);
    __bf16* Kb    = (__bf16*)(ws + 24 * MB);
    __bf16* Vb    = (__bf16*)(ws + 32 * MB);
    __bf16* attnb = (__bf16*)(ws + 40 * MB);   // ends at 48 MiB

    const int nX = T_SEQ * DM / 4;
    const int nW = DM * DM / 4;
    cvt_bf16<<<(nX + 255) / 256, 256, 0, stream>>>(x, xb, nX);
    cvt4_bf16<<<dim3((nW + 255) / 256, 4), 256, 0, stream>>>(Wq, Wk, Wv, Wo,
                                                             wqb, wkb, wvb, wob, nW);

    gemm_qkv<<<dim3(DM / 128, T_SEQ / 128, 3), 256, 0, stream>>>(xb, wqb, wkb, wvb, Qb, Kb, Vb);

    vtrans<<<dim3(T_SEQ / 64, NH), 256, 0, stream>>>(Vb, VtG);

    attn_fwd<<<dim3(T_SEQ / 128, NH), 256, 0, stream>>>(Qb, Kb, VtG, attnb);

    gemm_out<<<dim3(DM / 128, T_SEQ / 128), 256, 0, stream>>>(attnb, wob, out);
}

// Round 4
// 190.604 us; speedup vs baseline: 1.7314x; 1.1762x over previous
//
#include <hip/hip_runtime.h>
#include <hip/hip_bf16.h>
#include <math.h>

typedef __attribute__((ext_vector_type(8)))  __bf16 bf16x8;
typedef __attribute__((ext_vector_type(4)))  __bf16 bf16x4;
typedef __attribute__((ext_vector_type(4)))  float  f32x4;
typedef __attribute__((ext_vector_type(16))) float  f32x16;

static constexpr int T_SEQ = 4096;
static constexpr int DM    = 1024;
static constexpr int NH    = 16;
// 1/sqrt(dk) * log2(e): softmax done in exp2 domain
static constexpr float QSCALE = 0.125f * 1.44269504088896340736f;

__device__ __forceinline__ void gload16(const void* g, void* l) {
    __builtin_amdgcn_global_load_lds(
        (const __attribute__((address_space(1))) unsigned int*)g,
        (__attribute__((address_space(3))) unsigned int*)l,
        16, 0, 0);
}

__device__ __forceinline__ unsigned cvtpk_bf16(float a, float b) {
    unsigned r;
    asm("v_cvt_pk_bf16_f32 %0, %1, %2" : "=v"(r) : "v"(a), "v"(b));
    return r;
}
// v_permlane32_swap_b32: vdst[32+i] <-> src[i]  (both results used)
__device__ __forceinline__ void permswap(unsigned& x, unsigned& y) {
    asm("v_permlane32_swap_b32 %0, %1" : "+v"(x), "+v"(y));
}

// ---------------- fp32 -> bf16 converts ----------------
__global__ __launch_bounds__(256)
void cvt_bf16(const float* __restrict__ in, __bf16* __restrict__ out, int n4) {
    int i = blockIdx.x * blockDim.x + threadIdx.x;
    if (i >= n4) return;
    float4 v = ((const float4*)in)[i];
    bf16x4 o;
    o[0] = (__bf16)v.x; o[1] = (__bf16)v.y; o[2] = (__bf16)v.z; o[3] = (__bf16)v.w;
    ((bf16x4*)out)[i] = o;
}

__global__ __launch_bounds__(256)
void cvt4_bf16(const float* __restrict__ a0, const float* __restrict__ a1,
               const float* __restrict__ a2, const float* __restrict__ a3,
               __bf16* __restrict__ o0, __bf16* __restrict__ o1,
               __bf16* __restrict__ o2, __bf16* __restrict__ o3, int n4) {
    int i = blockIdx.x * blockDim.x + threadIdx.x;
    if (i >= n4) return;
    const float* in = blockIdx.y == 0 ? a0 : blockIdx.y == 1 ? a1 : blockIdx.y == 2 ? a2 : a3;
    __bf16* out     = blockIdx.y == 0 ? o0 : blockIdx.y == 1 ? o1 : blockIdx.y == 2 ? o2 : o3;
    float4 v = ((const float4*)in)[i];
    bf16x4 o;
    o[0] = (__bf16)v.x; o[1] = (__bf16)v.y; o[2] = (__bf16)v.z; o[3] = (__bf16)v.w;
    ((bf16x4*)out)[i] = o;
}

// ---------------- GEMM body: C = A @ B^T (m97 structure) ----------------
template<bool OUT_BF16>
__device__ __forceinline__ void gemm_body(const __bf16* __restrict__ A,
                                          const __bf16* __restrict__ B,
                                          void* __restrict__ Cout,
                                          int N, int K, float scale,
                                          int bx, int by) {
    __shared__ __align__(16) __bf16 Al[128 * 64];
    __shared__ __align__(16) __bf16 Bl[128 * 64];
    const int tid  = threadIdx.x;
    const int lane = tid & 63;
    const int wid  = tid >> 6;
    const int wr   = wid >> 1, wc = wid & 1;
    const int m0   = by * 128, n0 = bx * 128;
    const int r    = lane & 15, g = lane >> 4;

    f32x4 acc[4][4];
    const f32x4 z4 = {0.f, 0.f, 0.f, 0.f};
    #pragma unroll
    for (int i = 0; i < 4; ++i)
        #pragma unroll
        for (int j = 0; j < 4; ++j) acc[i][j] = z4;

    for (int kt = 0; kt < K; kt += 64) {
        __syncthreads();
        #pragma unroll
        for (int p = 0; p < 4; ++p) {
            int u    = p * 256 + tid;
            int row  = u >> 3;
            int col8 = (u & 7) ^ (row & 7);
            gload16(A + (size_t)(m0 + row) * K + kt + col8 * 8,
                    (char*)Al + (p * 256 + wid * 64) * 16);
            gload16(B + (size_t)(n0 + row) * K + kt + col8 * 8,
                    (char*)Bl + (p * 256 + wid * 64) * 16);
        }
        __syncthreads();
        __builtin_amdgcn_s_setprio(1);
        #pragma unroll
        for (int kk = 0; kk < 2; ++kk) {
            bf16x8 af[4], bfr[4];
            #pragma unroll
            for (int mi = 0; mi < 4; ++mi)
                af[mi] = *(const bf16x8*)&Al[(wr * 64 + mi * 16 + r) * 64 + (((kk * 4 + g) ^ (r & 7)) * 8)];
            #pragma unroll
            for (int nj = 0; nj < 4; ++nj)
                bfr[nj] = *(const bf16x8*)&Bl[(wc * 64 + nj * 16 + r) * 64 + (((kk * 4 + g) ^ (r & 7)) * 8)];
            #pragma unroll
            for (int mi = 0; mi < 4; ++mi)
                #pragma unroll
                for (int nj = 0; nj < 4; ++nj)
                    acc[mi][nj] = __builtin_amdgcn_mfma_f32_16x16x32_bf16(af[mi], bfr[nj], acc[mi][nj], 0, 0, 0);
        }
        __builtin_amdgcn_s_setprio(0);
    }
    #pragma unroll
    for (int mi = 0; mi < 4; ++mi)
        #pragma unroll
        for (int nj = 0; nj < 4; ++nj)
            #pragma unroll
            for (int j = 0; j < 4; ++j) {
                int row = m0 + wr * 64 + mi * 16 + g * 4 + j;
                int col = n0 + wc * 64 + nj * 16 + r;
                float v = acc[mi][nj][j] * scale;
                if (OUT_BF16) ((__bf16*)Cout)[(size_t)row * N + col] = (__bf16)v;
                else          ((float*)Cout)[(size_t)row * N + col]  = v;
            }
}

__global__ __launch_bounds__(256)
void gemm_qkv(const __bf16* __restrict__ A,
              const __bf16* __restrict__ W0, const __bf16* __restrict__ W1,
              const __bf16* __restrict__ W2,
              __bf16* __restrict__ O0, __bf16* __restrict__ O1, __bf16* __restrict__ O2) {
    const int z = blockIdx.z;
    const __bf16* B = z == 0 ? W0 : (z == 1 ? W1 : W2);
    __bf16*       C = z == 0 ? O0 : (z == 1 ? O1 : O2);
    float scale = z == 0 ? QSCALE : 1.0f;
    gemm_body<true>(A, B, C, DM, DM, scale, blockIdx.x, blockIdx.y);
}

__global__ __launch_bounds__(256)
void gemm_out(const __bf16* __restrict__ A, const __bf16* __restrict__ B,
              float* __restrict__ C) {
    gemm_body<false>(A, B, C, DM, DM, 1.0f, blockIdx.x, blockIdx.y);
}

// ---------------- V transpose: Vt[h*64+d][t] = V[t][h*64+d] ----------------
__global__ __launch_bounds__(256)
void vtrans(const __bf16* __restrict__ V, __bf16* __restrict__ Vt) {
    __shared__ __bf16 tl[64][72];
    const int tid = threadIdx.x;
    const int t0  = blockIdx.x * 64;
    const int h   = blockIdx.y;
    #pragma unroll
    for (int p = 0; p < 2; ++p) {
        int c = p * 256 + tid, row = c >> 3, col8 = c & 7;
        *(bf16x8*)&tl[row][col8 * 8] =
            *(const bf16x8*)(V + (size_t)(t0 + row) * DM + h * 64 + col8 * 8);
    }
    __syncthreads();
    #pragma unroll
    for (int p = 0; p < 2; ++p) {
        int c = p * 256 + tid, d = c >> 3, tc8 = c & 7;
        bf16x8 o;
        #pragma unroll
        for (int e = 0; e < 8; ++e) o[e] = tl[tc8 * 8 + e][d];
        *(bf16x8*)(Vt + (size_t)(h * 64 + d) * T_SEQ + t0 + tc8 * 8) = o;
    }
}

// ---------------- causal flash attention v4 ----------------
// 2 waves/block, 64 q-rows/block (32/wave), KVBLK=64, grid (NH, T/64) so the
// whole grid is co-resident (5 blocks/CU by LDS). Swapped QK^T, in-register
// softmax with defer-max (THR=8), P via cvt_pk+permlane32_swap, O^T accum.
__global__ __launch_bounds__(128)
void attn_fwd(const __bf16* __restrict__ Q, const __bf16* __restrict__ Kp,
              const __bf16* __restrict__ Vt, __bf16* __restrict__ O)
{
    __shared__ __align__(16) __bf16 Kl[2][64 * 64];
    __shared__ __align__(16) __bf16 Vl[2][64 * 64];
    const int tid  = threadIdx.x;
    const int lane = tid & 63, wid = tid >> 6;
    const int l31  = lane & 31;
    const int hi   = lane >> 5;
    const int h    = blockIdx.x;                        // head-major dispatch
    const int qb   = (T_SEQ / 64 - 1) - blockIdx.y;     // heavy q-tiles first
    const int qw   = qb * 64 + wid * 32;                // wave's first q row
    const int qg   = qw + l31;                          // this lane's q row

    // Q fragments (B-operand): qf[kd0] = Q[qg][kd0*16 + hi*8 .. +7]
    bf16x8 qf[4];
    #pragma unroll
    for (int kd0 = 0; kd0 < 4; ++kd0)
        qf[kd0] = *(const bf16x8*)(Q + (size_t)qg * DM + h * 64 + kd0 * 16 + hi * 8);

    float m_i = -1e30f, l_i = 0.f;
    f32x16 oacc[2];
    #pragma unroll
    for (int d = 0; d < 2; ++d)
        #pragma unroll
        for (int e = 0; e < 16; ++e) oacc[d][e] = 0.f;

    const int nt = qb + 1;

    auto stage = [&](int t, int buf) {
        #pragma unroll
        for (int p = 0; p < 4; ++p) {
            int u    = p * 128 + tid;          // 16B unit, 0..511
            int row  = u >> 3;
            int col8 = (u & 7) ^ (row & 7);
            gload16(Kp + (size_t)(t * 64 + row) * DM + h * 64 + col8 * 8,
                    (char*)&Kl[buf][0] + (p * 128 + wid * 64) * 16);
            gload16(Vt + (size_t)(h * 64 + row) * T_SEQ + t * 64 + col8 * 8,
                    (char*)&Vl[buf][0] + (p * 128 + wid * 64) * 16);
        }
    };

    stage(0, 0);
    int cur = 0;
    for (int t = 0; t < nt; ++t) {
        __syncthreads();                    // buf[cur] staged; prev compute done
        if (t + 1 < nt) stage(t + 1, cur ^ 1);
        // ---- S^T = K Q^T : sf[ksub][reg] = S[qg][t*64+ksub*32+pat(reg)+4*hi]
        f32x16 sf[2];
        #pragma unroll
        for (int ks = 0; ks < 2; ++ks)
            #pragma unroll
            for (int e = 0; e < 16; ++e) sf[ks][e] = 0.f;
        __builtin_amdgcn_s_setprio(1);
        #pragma unroll
        for (int ksub = 0; ksub < 2; ++ksub) {
            const int row = ksub * 32 + l31;
            #pragma unroll
            for (int kd0 = 0; kd0 < 4; ++kd0) {
                bf16x8 kf = *(const bf16x8*)
                    &Kl[cur][(row << 6) + ((((kd0 << 1) + hi) ^ (row & 7)) << 3)];
                sf[ksub] = __builtin_amdgcn_mfma_f32_32x32x16_bf16(kf, qf[kd0], sf[ksub], 0, 0, 0);
            }
        }
        __builtin_amdgcn_s_setprio(0);
        // ---- causal mask (diagonal tile only) ----
        if (t == qb) {
            const int kb = (t << 6) + 4 * hi;
            #pragma unroll
            for (int ksub = 0; ksub < 2; ++ksub)
                #pragma unroll
                for (int e = 0; e < 16; ++e) {
                    int k = kb + ksub * 32 + ((e & 3) + 8 * (e >> 2));
                    if (k > qg) sf[ksub][e] = -1e30f;
                }
        }
        // ---- online softmax, in-register, defer-max ----
        float pm;
        {
            float t0[8];
            #pragma unroll
            for (int e = 0; e < 8; ++e)
                t0[e] = fmaxf(fmaxf(sf[0][e], sf[0][e + 8]), fmaxf(sf[1][e], sf[1][e + 8]));
            #pragma unroll
            for (int s = 4; s > 0; s >>= 1)
                #pragma unroll
                for (int e = 0; e < s; ++e) t0[e] = fmaxf(t0[e], t0[e + s]);
            pm = t0[0];
        }
        pm = fmaxf(pm, __shfl_xor(pm, 32));
        if (pm > m_i + 8.f) {               // defer-max: rescale only on growth
            float al = exp2f(m_i - pm);
            m_i = pm;
            l_i *= al;
            #pragma unroll
            for (int d = 0; d < 2; ++d)
                #pragma unroll
                for (int e = 0; e < 16; ++e) oacc[d][e] *= al;
        }
        float p[32];
        #pragma unroll
        for (int i = 0; i < 32; ++i)
            p[i] = exp2f(sf[i >> 4][i & 15] - m_i);
        {
            float s0[8];
            #pragma unroll
            for (int e = 0; e < 8; ++e)
                s0[e] = (p[e] + p[e + 8]) + (p[e + 16] + p[e + 24]);
            #pragma unroll
            for (int s = 4; s > 0; s >>= 1)
                #pragma unroll
                for (int e = 0; e < s; ++e) s0[e] += s0[e + s];
            float rs = s0[0];
            rs += __shfl_xor(rs, 32);
            l_i += rs;
        }
        // ---- P -> bf16 fragments (cvt_pk + permlane32_swap), O^T += V^T P^T
        __builtin_amdgcn_s_setprio(1);
        #pragma unroll
        for (int ks = 0; ks < 4; ++ks) {
            unsigned w0 = cvtpk_bf16(p[8 * ks + 0], p[8 * ks + 1]);
            unsigned w1 = cvtpk_bf16(p[8 * ks + 2], p[8 * ks + 3]);
            unsigned w2 = cvtpk_bf16(p[8 * ks + 4], p[8 * ks + 5]);
            unsigned w3 = cvtpk_bf16(p[8 * ks + 6], p[8 * ks + 7]);
            permswap(w0, w2);
            permswap(w1, w3);
            union { unsigned u[4]; bf16x8 v; } pu;
            pu.u[0] = w0; pu.u[1] = w1; pu.u[2] = w2; pu.u[3] = w3;
            #pragma unroll
            for (int dsub = 0; dsub < 2; ++dsub) {
                const int row = dsub * 32 + l31;
                bf16x8 vt = *(const bf16x8*)
                    &Vl[cur][(row << 6) + ((((ks << 1) + hi) ^ (row & 7)) << 3)];
                oacc[dsub] = __builtin_amdgcn_mfma_f32_32x32x16_bf16(vt, pu.v, oacc[dsub], 0, 0, 0);
            }
        }
        __builtin_amdgcn_s_setprio(0);
        cur ^= 1;
    }
    // ---- epilogue: normalize, transpose via per-wave LDS, coalesced store ----
    __syncthreads();
    __bf16* ow = &Kl[0][0] + wid * 2048;   // per-wave [32 q][64 d], 16B-swizzled
    const float invl = 1.f / l_i;
    #pragma unroll
    for (int dsub = 0; dsub < 2; ++dsub)
        #pragma unroll
        for (int e = 0; e < 16; ++e) {
            int d = dsub * 32 + ((e & 3) + 8 * (e >> 2)) + 4 * hi;
            float v = oacc[dsub][e] * invl;
            int bo = l31 * 128 + ((2 * d) ^ ((l31 & 7) << 4));
            *(__bf16*)((char*)ow + bo) = (__bf16)v;
        }
    #pragma unroll
    for (int i = 0; i < 4; ++i) {
        int u  = hi * 4 + i;
        int bo = l31 * 128 + ((u * 16) ^ ((l31 & 7) << 4));
        bf16x8 v8 = *(const bf16x8*)((char*)ow + bo);
        *(bf16x8*)(O + (size_t)qg * DM + h * 64 + u * 8) = v8;
    }
}

extern "C" void kernel_launch(void* const* d_in, const int* in_sizes, int n_in,
                              void* d_out, int out_size, void* d_ws, size_t ws_size,
                              hipStream_t stream) {
    const float* x  = (const float*)d_in[0];
    const float* Wq = (const float*)d_in[1];
    const float* Wk = (const float*)d_in[2];
    const float* Wv = (const float*)d_in[3];
    const float* Wo = (const float*)d_in[4];
    float* out = (float*)d_out;

    char* ws = (char*)d_ws;
    const size_t MB = (size_t)1 << 20;
    __bf16* xb    = (__bf16*)(ws + 0 * MB);    // 8 MiB (dead after QKV gemms)
    __bf16* VtG   = (__bf16*)(ws + 0 * MB);    // reuses xb region
    __bf16* wqb   = (__bf16*)(ws + 8 * MB);
    __bf16* wkb   = (__bf16*)(ws + 10 * MB);
    __bf16* wvb   = (__bf16*)(ws + 12 * MB);
    __bf16* wob   = (__bf16*)(ws + 14 * MB);
    __bf16* Qb    = (__bf16*)(ws + 16 * MB);
    __bf16* Kb    = (__bf16*)(ws + 24 * MB);
    __bf16* Vb    = (__bf16*)(ws + 32 * MB);
    __bf16* attnb = (__bf16*)(ws + 40 * MB);   // ends at 48 MiB

    const int nX = T_SEQ * DM / 4;
    const int nW = DM * DM / 4;
    cvt_bf16<<<(nX + 255) / 256, 256, 0, stream>>>(x, xb, nX);
    cvt4_bf16<<<dim3((nW + 255) / 256, 4), 256, 0, stream>>>(Wq, Wk, Wv, Wo,
                                                             wqb, wkb, wvb, wob, nW);

    gemm_qkv<<<dim3(DM / 128, T_SEQ / 128, 3), 256, 0, stream>>>(xb, wqb, wkb, wvb, Qb, Kb, Vb);

    vtrans<<<dim3(T_SEQ / 64, NH), 256, 0, stream>>>(Vb, VtG);

    attn_fwd<<<dim3(NH, T_SEQ / 64), 128, 0, stream>>>(Qb, Kb, VtG, attnb);

    gemm_out<<<dim3(DM / 128, T_SEQ / 128), 256, 0, stream>>>(attnb, wob, out);
}

// Round 6
// 189.875 us; speedup vs baseline: 1.7381x; 1.0038x over previous
//
#include <hip/hip_runtime.h>
#include <hip/hip_bf16.h>
#include <math.h>

typedef __attribute__((ext_vector_type(8)))  __bf16 bf16x8;
typedef __attribute__((ext_vector_type(4)))  __bf16 bf16x4;
typedef __attribute__((ext_vector_type(4)))  float  f32x4;
typedef __attribute__((ext_vector_type(16))) float  f32x16;

static constexpr int T_SEQ = 4096;
static constexpr int DM    = 1024;
static constexpr int NH    = 16;
// 1/sqrt(dk) * log2(e): softmax done in exp2 domain
static constexpr float QSCALE = 0.125f * 1.44269504088896340736f;

__device__ __forceinline__ void gload16(const void* g, void* l) {
    __builtin_amdgcn_global_load_lds(
        (const __attribute__((address_space(1))) unsigned int*)g,
        (__attribute__((address_space(3))) unsigned int*)l,
        16, 0, 0);
}

__device__ __forceinline__ unsigned cvtpk_bf16(float a, float b) {
    unsigned r;
    asm("v_cvt_pk_bf16_f32 %0, %1, %2" : "=v"(r) : "v"(a), "v"(b));
    return r;
}
// v_permlane32_swap_b32: exchanges lane<32 / lane>=32 halves between x and y
__device__ __forceinline__ void permswap(unsigned& x, unsigned& y) {
    asm("v_permlane32_swap_b32 %0, %1" : "+v"(x), "+v"(y));
}
// cross-half (lane^32) reduce. The empty asm makes b a distinct SSA value so
// the allocator CANNOT coalesce a/b into one VGPR (which would degenerate the
// swap into an in-place half-swap -> wrong max -> inf/NaN; round-5 bug).
__device__ __forceinline__ float xhalf_max(float v) {
    union { float f; unsigned u; } a, b;
    a.f = v; b.f = v;
    asm volatile("" : "+v"(b.u));
    permswap(a.u, b.u);
    return fmaxf(a.f, b.f);
}
__device__ __forceinline__ float xhalf_sum(float v) {
    union { float f; unsigned u; } a, b;
    a.f = v; b.f = v;
    asm volatile("" : "+v"(b.u));
    permswap(a.u, b.u);
    return a.f + b.f;
}

// ---------------- fp32 -> bf16 converts ----------------
__global__ __launch_bounds__(256)
void cvt_bf16(const float* __restrict__ in, __bf16* __restrict__ out, int n4) {
    int i = blockIdx.x * blockDim.x + threadIdx.x;
    if (i >= n4) return;
    float4 v = ((const float4*)in)[i];
    bf16x4 o;
    o[0] = (__bf16)v.x; o[1] = (__bf16)v.y; o[2] = (__bf16)v.z; o[3] = (__bf16)v.w;
    ((bf16x4*)out)[i] = o;
}

__global__ __launch_bounds__(256)
void cvt4_bf16(const float* __restrict__ a0, const float* __restrict__ a1,
               const float* __restrict__ a2, const float* __restrict__ a3,
               __bf16* __restrict__ o0, __bf16* __restrict__ o1,
               __bf16* __restrict__ o2, __bf16* __restrict__ o3, int n4) {
    int i = blockIdx.x * blockDim.x + threadIdx.x;
    if (i >= n4) return;
    const float* in = blockIdx.y == 0 ? a0 : blockIdx.y == 1 ? a1 : blockIdx.y == 2 ? a2 : a3;
    __bf16* out     = blockIdx.y == 0 ? o0 : blockIdx.y == 1 ? o1 : blockIdx.y == 2 ? o2 : o3;
    float4 v = ((const float4*)in)[i];
    bf16x4 o;
    o[0] = (__bf16)v.x; o[1] = (__bf16)v.y; o[2] = (__bf16)v.z; o[3] = (__bf16)v.w;
    ((bf16x4*)out)[i] = o;
}

// ---------------- GEMM body: C = A @ B^T (m97 structure) ----------------
template<bool OUT_BF16>
__device__ __forceinline__ void gemm_body(const __bf16* __restrict__ A,
                                          const __bf16* __restrict__ B,
                                          void* __restrict__ Cout,
                                          int N, int K, float scale,
                                          int bx, int by) {
    __shared__ __align__(16) __bf16 Al[128 * 64];
    __shared__ __align__(16) __bf16 Bl[128 * 64];
    const int tid  = threadIdx.x;
    const int lane = tid & 63;
    const int wid  = tid >> 6;
    const int wr   = wid >> 1, wc = wid & 1;
    const int m0   = by * 128, n0 = bx * 128;
    const int r    = lane & 15, g = lane >> 4;

    f32x4 acc[4][4];
    const f32x4 z4 = {0.f, 0.f, 0.f, 0.f};
    #pragma unroll
    for (int i = 0; i < 4; ++i)
        #pragma unroll
        for (int j = 0; j < 4; ++j) acc[i][j] = z4;

    for (int kt = 0; kt < K; kt += 64) {
        __syncthreads();
        #pragma unroll
        for (int p = 0; p < 4; ++p) {
            int u    = p * 256 + tid;
            int row  = u >> 3;
            int col8 = (u & 7) ^ (row & 7);
            gload16(A + (size_t)(m0 + row) * K + kt + col8 * 8,
                    (char*)Al + (p * 256 + wid * 64) * 16);
            gload16(B + (size_t)(n0 + row) * K + kt + col8 * 8,
                    (char*)Bl + (p * 256 + wid * 64) * 16);
        }
        __syncthreads();
        __builtin_amdgcn_s_setprio(1);
        #pragma unroll
        for (int kk = 0; kk < 2; ++kk) {
            bf16x8 af[4], bfr[4];
            #pragma unroll
            for (int mi = 0; mi < 4; ++mi)
                af[mi] = *(const bf16x8*)&Al[(wr * 64 + mi * 16 + r) * 64 + (((kk * 4 + g) ^ (r & 7)) * 8)];
            #pragma unroll
            for (int nj = 0; nj < 4; ++nj)
                bfr[nj] = *(const bf16x8*)&Bl[(wc * 64 + nj * 16 + r) * 64 + (((kk * 4 + g) ^ (r & 7)) * 8)];
            #pragma unroll
            for (int mi = 0; mi < 4; ++mi)
                #pragma unroll
                for (int nj = 0; nj < 4; ++nj)
                    acc[mi][nj] = __builtin_amdgcn_mfma_f32_16x16x32_bf16(af[mi], bfr[nj], acc[mi][nj], 0, 0, 0);
        }
        __builtin_amdgcn_s_setprio(0);
    }
    #pragma unroll
    for (int mi = 0; mi < 4; ++mi)
        #pragma unroll
        for (int nj = 0; nj < 4; ++nj)
            #pragma unroll
            for (int j = 0; j < 4; ++j) {
                int row = m0 + wr * 64 + mi * 16 + g * 4 + j;
                int col = n0 + wc * 64 + nj * 16 + r;
                float v = acc[mi][nj][j] * scale;
                if (OUT_BF16) ((__bf16*)Cout)[(size_t)row * N + col] = (__bf16)v;
                else          ((float*)Cout)[(size_t)row * N + col]  = v;
            }
}

__global__ __launch_bounds__(256)
void gemm_qkv(const __bf16* __restrict__ A,
              const __bf16* __restrict__ W0, const __bf16* __restrict__ W1,
              const __bf16* __restrict__ W2,
              __bf16* __restrict__ O0, __bf16* __restrict__ O1, __bf16* __restrict__ O2) {
    const int z = blockIdx.z;
    const __bf16* B = z == 0 ? W0 : (z == 1 ? W1 : W2);
    __bf16*       C = z == 0 ? O0 : (z == 1 ? O1 : O2);
    float scale = z == 0 ? QSCALE : 1.0f;
    gemm_body<true>(A, B, C, DM, DM, scale, blockIdx.x, blockIdx.y);
}

__global__ __launch_bounds__(256)
void gemm_out(const __bf16* __restrict__ A, const __bf16* __restrict__ B,
              float* __restrict__ C) {
    gemm_body<false>(A, B, C, DM, DM, 1.0f, blockIdx.x, blockIdx.y);
}

// ---------------- V transpose: Vt[h*64+d][t] = V[t][h*64+d] ----------------
__global__ __launch_bounds__(256)
void vtrans(const __bf16* __restrict__ V, __bf16* __restrict__ Vt) {
    __shared__ __bf16 tl[64][72];
    const int tid = threadIdx.x;
    const int t0  = blockIdx.x * 64;
    const int h   = blockIdx.y;
    #pragma unroll
    for (int p = 0; p < 2; ++p) {
        int c = p * 256 + tid, row = c >> 3, col8 = c & 7;
        *(bf16x8*)&tl[row][col8 * 8] =
            *(const bf16x8*)(V + (size_t)(t0 + row) * DM + h * 64 + col8 * 8);
    }
    __syncthreads();
    #pragma unroll
    for (int p = 0; p < 2; ++p) {
        int c = p * 256 + tid, d = c >> 3, tc8 = c & 7;
        bf16x8 o;
        #pragma unroll
        for (int e = 0; e < 8; ++e) o[e] = tl[tc8 * 8 + e][d];
        *(bf16x8*)(Vt + (size_t)(h * 64 + d) * T_SEQ + t0 + tc8 * 8) = o;
    }
}

// ---------------- causal flash attention v5b ----------------
// 2 waves/block, 64 q-rows/block, grid (NH, 64) with equal-sum qb scramble
// so every CU's resident blocks carry identical total work. T15 pipeline:
// QK(t+1) MFMA overlaps softmax(t) VALU; tile t+2 reg-staged (T14) and
// ds_written after the reads-done barrier. Cross-half reduce via permlane.
__global__ __launch_bounds__(128)
void attn_fwd(const __bf16* __restrict__ Q, const __bf16* __restrict__ Kp,
              const __bf16* __restrict__ Vt, __bf16* __restrict__ O)
{
    __shared__ __align__(16) __bf16 Kl[2][64 * 64];
    __shared__ __align__(16) __bf16 Vl[2][64 * 64];
    const int tid  = threadIdx.x;
    const int lane = tid & 63, wid = tid >> 6;
    const int l31  = lane & 31;
    const int hi   = lane >> 5;
    const int h    = blockIdx.x;                 // head-major: head h -> XCD h%8
    // equal-sum partition {u, 31-u, 32+u, 63-u}: CU's 4 blocks sum to 130 tiles
    const int u_   = blockIdx.y & 15, j_ = blockIdx.y >> 4;
    const int qb   = j_ == 0 ? u_ : j_ == 1 ? 31 - u_ : j_ == 2 ? 32 + u_ : 63 - u_;
    const int qw   = qb * 64 + wid * 32;         // wave's first q row
    const int qg   = qw + l31;                   // this lane's q row

    // Q fragments (B-operand): qf[kd0] = Q[qg][kd0*16 + hi*8 .. +7]
    bf16x8 qf[4];
    #pragma unroll
    for (int kd0 = 0; kd0 < 4; ++kd0)
        qf[kd0] = *(const bf16x8*)(Q + (size_t)qg * DM + h * 64 + kd0 * 16 + hi * 8);

    float m_i = -1e30f, l_i = 0.f;
    f32x16 oacc[2];
    #pragma unroll
    for (int d = 0; d < 2; ++d)
        #pragma unroll
        for (int e = 0; e < 16; ++e) oacc[d][e] = 0.f;

    const int nt = qb + 1;

    // prologue: stage tiles 0 (and 1) via global_load_lds
    auto stage_lds = [&](int t, int buf) {
        #pragma unroll
        for (int p = 0; p < 4; ++p) {
            int u    = p * 128 + tid;          // 16B unit, 0..511
            int row  = u >> 3;
            int col8 = (u & 7) ^ (row & 7);
            gload16(Kp + (size_t)(t * 64 + row) * DM + h * 64 + col8 * 8,
                    (char*)&Kl[buf][0] + (p * 128 + wid * 64) * 16);
            gload16(Vt + (size_t)(h * 64 + row) * T_SEQ + t * 64 + col8 * 8,
                    (char*)&Vl[buf][0] + (p * 128 + wid * 64) * 16);
        }
    };
    stage_lds(0, 0);
    if (nt > 1) stage_lds(1, 1);
    __syncthreads();

    auto qk = [&](f32x16* sdst, int buf) {
        #pragma unroll
        for (int ksub = 0; ksub < 2; ++ksub) {
            const int row = ksub * 32 + l31;
            f32x16 a;
            #pragma unroll
            for (int e = 0; e < 16; ++e) a[e] = 0.f;
            #pragma unroll
            for (int kd0 = 0; kd0 < 4; ++kd0) {
                bf16x8 kf = *(const bf16x8*)
                    &Kl[buf][(row << 6) + ((((kd0 << 1) + hi) ^ (row & 7)) << 3)];
                a = __builtin_amdgcn_mfma_f32_32x32x16_bf16(kf, qf[kd0], a, 0, 0, 0);
            }
            sdst[ksub] = a;
        }
    };
    auto mask_sf = [&](f32x16* s, int t) {
        const int kb = (t << 6) + 4 * hi;
        #pragma unroll
        for (int ksub = 0; ksub < 2; ++ksub)
            #pragma unroll
            for (int e = 0; e < 16; ++e) {
                int k = kb + ksub * 32 + ((e & 3) + 8 * (e >> 2));
                if (k > qg) s[ksub][e] = -1e30f;
            }
    };

    // sf holds S(t) at loop top
    f32x16 sf[2], sfn[2];
    qk(sf, 0);
    if (qb == 0) mask_sf(sf, 0);

    bf16x8 kreg[4], vreg[4];
    for (int t = 0; t < nt; ++t) {
        const int cur = t & 1;
        const bool have_next  = (t + 1 < nt);
        const bool have_next2 = (t + 2 < nt);
        // A) issue reg-staged loads for tile t+2 (in flight across whole body)
        if (have_next2) {
            const int t2 = t + 2;
            #pragma unroll
            for (int p = 0; p < 4; ++p) {
                int u   = p * 128 + tid;
                int row = u >> 3;
                int c   = u & 7;
                kreg[p] = *(const bf16x8*)(Kp + (size_t)(t2 * 64 + row) * DM + h * 64 + c * 8);
                vreg[p] = *(const bf16x8*)(Vt + (size_t)(h * 64 + row) * T_SEQ + t2 * 64 + c * 8);
            }
        }
        // B) QK(t+1) — MFMA, independent of softmax(t): overlaps it
        __builtin_amdgcn_s_setprio(1);
        if (have_next) {
            qk(sfn, cur ^ 1);
            if (t + 1 == qb) mask_sf(sfn, t + 1);
        }
        __builtin_amdgcn_s_setprio(0);
        // C) softmax(t) — VALU
        float pm;
        {
            float t0[8];
            #pragma unroll
            for (int e = 0; e < 8; ++e)
                t0[e] = fmaxf(fmaxf(sf[0][e], sf[0][e + 8]), fmaxf(sf[1][e], sf[1][e + 8]));
            #pragma unroll
            for (int s = 4; s > 0; s >>= 1)
                #pragma unroll
                for (int e = 0; e < s; ++e) t0[e] = fmaxf(t0[e], t0[e + s]);
            pm = xhalf_max(t0[0]);
        }
        if (pm > m_i + 8.f) {               // defer-max rescale
            float al = exp2f(m_i - pm);
            m_i = pm;
            l_i *= al;
            #pragma unroll
            for (int d = 0; d < 2; ++d)
                #pragma unroll
                for (int e = 0; e < 16; ++e) oacc[d][e] *= al;
        }
        float p[32];
        #pragma unroll
        for (int i = 0; i < 32; ++i)
            p[i] = exp2f(sf[i >> 4][i & 15] - m_i);
        {
            float s0[8];
            #pragma unroll
            for (int e = 0; e < 8; ++e)
                s0[e] = (p[e] + p[e + 8]) + (p[e + 16] + p[e + 24]);
            #pragma unroll
            for (int s = 4; s > 0; s >>= 1)
                #pragma unroll
                for (int e = 0; e < s; ++e) s0[e] += s0[e + s];
            l_i += xhalf_sum(s0[0]);
        }
        // D) PV(t): P->bf16 frags (cvt_pk + permlane32_swap), O^T += V^T P^T
        __builtin_amdgcn_s_setprio(1);
        #pragma unroll
        for (int ks = 0; ks < 4; ++ks) {
            unsigned w0 = cvtpk_bf16(p[8 * ks + 0], p[8 * ks + 1]);
            unsigned w1 = cvtpk_bf16(p[8 * ks + 2], p[8 * ks + 3]);
            unsigned w2 = cvtpk_bf16(p[8 * ks + 4], p[8 * ks + 5]);
            unsigned w3 = cvtpk_bf16(p[8 * ks + 6], p[8 * ks + 7]);
            permswap(w0, w2);
            permswap(w1, w3);
            union { unsigned u[4]; bf16x8 v; } pu;
            pu.u[0] = w0; pu.u[1] = w1; pu.u[2] = w2; pu.u[3] = w3;
            #pragma unroll
            for (int dsub = 0; dsub < 2; ++dsub) {
                const int row = dsub * 32 + l31;
                bf16x8 vt = *(const bf16x8*)
                    &Vl[cur][(row << 6) + ((((ks << 1) + hi) ^ (row & 7)) << 3)];
                oacc[dsub] = __builtin_amdgcn_mfma_f32_32x32x16_bf16(vt, pu.v, oacc[dsub], 0, 0, 0);
            }
        }
        __builtin_amdgcn_s_setprio(0);
        // E) commit tile t+2 into buf[cur] once all reads of buf[cur] are done
        if (have_next2) {
            __syncthreads();                 // all waves done reading buf[cur]
            #pragma unroll
            for (int p = 0; p < 4; ++p) {
                int u   = p * 128 + tid;
                int row = u >> 3;
                int c   = u & 7;
                *(bf16x8*)&Kl[cur][(row << 6) + ((c ^ (row & 7)) << 3)] = kreg[p];
                *(bf16x8*)&Vl[cur][(row << 6) + ((c ^ (row & 7)) << 3)] = vreg[p];
            }
            __syncthreads();                 // writes visible to both waves
        }
        if (have_next) {                     // guard: never copy uninitialized sfn
            sf[0] = sfn[0];
            sf[1] = sfn[1];
        }
    }
    // ---- epilogue: normalize, transpose via per-wave LDS, coalesced store ----
    __syncthreads();
    __bf16* ow = &Kl[0][0] + wid * 2048;   // per-wave [32 q][64 d], 16B-swizzled
    const float invl = 1.f / l_i;
    #pragma unroll
    for (int dsub = 0; dsub < 2; ++dsub)
        #pragma unroll
        for (int e = 0; e < 16; ++e) {
            int d = dsub * 32 + ((e & 3) + 8 * (e >> 2)) + 4 * hi;
            float v = oacc[dsub][e] * invl;
            int bo = l31 * 128 + ((2 * d) ^ ((l31 & 7) << 4));
            *(__bf16*)((char*)ow + bo) = (__bf16)v;
        }
    #pragma unroll
    for (int i = 0; i < 4; ++i) {
        int u  = hi * 4 + i;
        int bo = l31 * 128 + ((u * 16) ^ ((l31 & 7) << 4));
        bf16x8 v8 = *(const bf16x8*)((char*)ow + bo);
        *(bf16x8*)(O + (size_t)qg * DM + h * 64 + u * 8) = v8;
    }
}

extern "C" void kernel_launch(void* const* d_in, const int* in_sizes, int n_in,
                              void* d_out, int out_size, void* d_ws, size_t ws_size,
                              hipStream_t stream) {
    const float* x  = (const float*)d_in[0];
    const float* Wq = (const float*)d_in[1];
    const float* Wk = (const float*)d_in[2];
    const float* Wv = (const float*)d_in[3];
    const float* Wo = (const float*)d_in[4];
    float* out = (float*)d_out;

    char* ws = (char*)d_ws;
    const size_t MB = (size_t)1 << 20;
    __bf16* xb    = (__bf16*)(ws + 0 * MB);    // 8 MiB (dead after QKV gemms)
    __bf16* VtG   = (__bf16*)(ws + 0 * MB);    // reuses xb region
    __bf16* wqb   = (__bf16*)(ws + 8 * MB);
    __bf16* wkb   = (__bf16*)(ws + 10 * MB);
    __bf16* wvb   = (__bf16*)(ws + 12 * MB);
    __bf16* wob   = (__bf16*)(ws + 14 * MB);
    __bf16* Qb    = (__bf16*)(ws + 16 * MB);
    __bf16* Kb    = (__bf16*)(ws + 24 * MB);
    __bf16* Vb    = (__bf16*)(ws + 32 * MB);
    __bf16* attnb = (__bf16*)(ws + 40 * MB);   // ends at 48 MiB

    const int nX = T_SEQ * DM / 4;
    const int nW = DM * DM / 4;
    cvt_bf16<<<(nX + 255) / 256, 256, 0, stream>>>(x, xb, nX);
    cvt4_bf16<<<dim3((nW + 255) / 256, 4), 256, 0, stream>>>(Wq, Wk, Wv, Wo,
                                                             wqb, wkb, wvb, wob, nW);

    gemm_qkv<<<dim3(DM / 128, T_SEQ / 128, 3), 256, 0, stream>>>(xb, wqb, wkb, wvb, Qb, Kb, Vb);

    vtrans<<<dim3(T_SEQ / 64, NH), 256, 0, stream>>>(Vb, VtG);

    attn_fwd<<<dim3(NH, 64), 128, 0, stream>>>(Qb, Kb, VtG, attnb);

    gemm_out<<<dim3(DM / 128, T_SEQ / 128), 256, 0, stream>>>(attnb, wob, out);
}

// Round 7
// 165.243 us; speedup vs baseline: 1.9971x; 1.1491x over previous
//
#include <hip/hip_runtime.h>
#include <hip/hip_bf16.h>
#include <math.h>

typedef __attribute__((ext_vector_type(8)))  __bf16 bf16x8;
typedef __attribute__((ext_vector_type(4)))  __bf16 bf16x4;
typedef __attribute__((ext_vector_type(4)))  float  f32x4;
typedef __attribute__((ext_vector_type(16))) float  f32x16;

static constexpr int T_SEQ = 4096;
static constexpr int DM    = 1024;
static constexpr int NH    = 16;
// split bookkeeping: q-tiles (64 rows) with qb >= SPLIT_QB are kv-split 2-way
static constexpr int SPLIT_QB   = 34;
static constexpr int SPLIT_ROWS = T_SEQ - SPLIT_QB * 64;   // 1920
// 1/sqrt(dk) * log2(e): softmax done in exp2 domain
static constexpr float QSCALE = 0.125f * 1.44269504088896340736f;

__device__ __forceinline__ void gload16(const void* g, void* l) {
    __builtin_amdgcn_global_load_lds(
        (const __attribute__((address_space(1))) unsigned int*)g,
        (__attribute__((address_space(3))) unsigned int*)l,
        16, 0, 0);
}

__device__ __forceinline__ unsigned cvtpk_bf16(float a, float b) {
    unsigned r;
    asm("v_cvt_pk_bf16_f32 %0, %1, %2" : "=v"(r) : "v"(a), "v"(b));
    return r;
}
// v_permlane32_swap_b32: exchanges lane<32 / lane>=32 halves between x and y
__device__ __forceinline__ void permswap(unsigned& x, unsigned& y) {
    asm("v_permlane32_swap_b32 %0, %1" : "+v"(x), "+v"(y));
}
// cross-half (lane^32) reduce. The empty asm makes b a distinct SSA value so
// the allocator cannot coalesce a/b into one VGPR (round-5 NaN bug).
__device__ __forceinline__ float xhalf_max(float v) {
    union { float f; unsigned u; } a, b;
    a.f = v; b.f = v;
    asm volatile("" : "+v"(b.u));
    permswap(a.u, b.u);
    return fmaxf(a.f, b.f);
}
__device__ __forceinline__ float xhalf_sum(float v) {
    union { float f; unsigned u; } a, b;
    a.f = v; b.f = v;
    asm volatile("" : "+v"(b.u));
    permswap(a.u, b.u);
    return a.f + b.f;
}

// ---------------- fp32 -> bf16 converts ----------------
__global__ __launch_bounds__(256)
void cvt_bf16(const float* __restrict__ in, __bf16* __restrict__ out, int n4) {
    int i = blockIdx.x * blockDim.x + threadIdx.x;
    if (i >= n4) return;
    float4 v = ((const float4*)in)[i];
    bf16x4 o;
    o[0] = (__bf16)v.x; o[1] = (__bf16)v.y; o[2] = (__bf16)v.z; o[3] = (__bf16)v.w;
    ((bf16x4*)out)[i] = o;
}

__global__ __launch_bounds__(256)
void cvt4_bf16(const float* __restrict__ a0, const float* __restrict__ a1,
               const float* __restrict__ a2, const float* __restrict__ a3,
               __bf16* __restrict__ o0, __bf16* __restrict__ o1,
               __bf16* __restrict__ o2, __bf16* __restrict__ o3, int n4) {
    int i = blockIdx.x * blockDim.x + threadIdx.x;
    if (i >= n4) return;
    const float* in = blockIdx.y == 0 ? a0 : blockIdx.y == 1 ? a1 : blockIdx.y == 2 ? a2 : a3;
    __bf16* out     = blockIdx.y == 0 ? o0 : blockIdx.y == 1 ? o1 : blockIdx.y == 2 ? o2 : o3;
    float4 v = ((const float4*)in)[i];
    bf16x4 o;
    o[0] = (__bf16)v.x; o[1] = (__bf16)v.y; o[2] = (__bf16)v.z; o[3] = (__bf16)v.w;
    ((bf16x4*)out)[i] = o;
}

// ---------------- GEMM body: C = A @ B^T (m97 structure) ----------------
template<bool OUT_BF16>
__device__ __forceinline__ void gemm_body(const __bf16* __restrict__ A,
                                          const __bf16* __restrict__ B,
                                          void* __restrict__ Cout,
                                          int N, int K, float scale,
                                          int bx, int by) {
    __shared__ __align__(16) __bf16 Al[128 * 64];
    __shared__ __align__(16) __bf16 Bl[128 * 64];
    const int tid  = threadIdx.x;
    const int lane = tid & 63;
    const int wid  = tid >> 6;
    const int wr   = wid >> 1, wc = wid & 1;
    const int m0   = by * 128, n0 = bx * 128;
    const int r    = lane & 15, g = lane >> 4;

    f32x4 acc[4][4];
    const f32x4 z4 = {0.f, 0.f, 0.f, 0.f};
    #pragma unroll
    for (int i = 0; i < 4; ++i)
        #pragma unroll
        for (int j = 0; j < 4; ++j) acc[i][j] = z4;

    for (int kt = 0; kt < K; kt += 64) {
        __syncthreads();
        #pragma unroll
        for (int p = 0; p < 4; ++p) {
            int u    = p * 256 + tid;
            int row  = u >> 3;
            int col8 = (u & 7) ^ (row & 7);
            gload16(A + (size_t)(m0 + row) * K + kt + col8 * 8,
                    (char*)Al + (p * 256 + wid * 64) * 16);
            gload16(B + (size_t)(n0 + row) * K + kt + col8 * 8,
                    (char*)Bl + (p * 256 + wid * 64) * 16);
        }
        __syncthreads();
        __builtin_amdgcn_s_setprio(1);
        #pragma unroll
        for (int kk = 0; kk < 2; ++kk) {
            bf16x8 af[4], bfr[4];
            #pragma unroll
            for (int mi = 0; mi < 4; ++mi)
                af[mi] = *(const bf16x8*)&Al[(wr * 64 + mi * 16 + r) * 64 + (((kk * 4 + g) ^ (r & 7)) * 8)];
            #pragma unroll
            for (int nj = 0; nj < 4; ++nj)
                bfr[nj] = *(const bf16x8*)&Bl[(wc * 64 + nj * 16 + r) * 64 + (((kk * 4 + g) ^ (r & 7)) * 8)];
            #pragma unroll
            for (int mi = 0; mi < 4; ++mi)
                #pragma unroll
                for (int nj = 0; nj < 4; ++nj)
                    acc[mi][nj] = __builtin_amdgcn_mfma_f32_16x16x32_bf16(af[mi], bfr[nj], acc[mi][nj], 0, 0, 0);
        }
        __builtin_amdgcn_s_setprio(0);
    }
    #pragma unroll
    for (int mi = 0; mi < 4; ++mi)
        #pragma unroll
        for (int nj = 0; nj < 4; ++nj)
            #pragma unroll
            for (int j = 0; j < 4; ++j) {
                int row = m0 + wr * 64 + mi * 16 + g * 4 + j;
                int col = n0 + wc * 64 + nj * 16 + r;
                float v = acc[mi][nj][j] * scale;
                if (OUT_BF16) ((__bf16*)Cout)[(size_t)row * N + col] = (__bf16)v;
                else          ((float*)Cout)[(size_t)row * N + col]  = v;
            }
}

__global__ __launch_bounds__(256)
void gemm_qkv(const __bf16* __restrict__ A,
              const __bf16* __restrict__ W0, const __bf16* __restrict__ W1,
              const __bf16* __restrict__ W2,
              __bf16* __restrict__ O0, __bf16* __restrict__ O1, __bf16* __restrict__ O2) {
    const int z = blockIdx.z;
    const __bf16* B = z == 0 ? W0 : (z == 1 ? W1 : W2);
    __bf16*       C = z == 0 ? O0 : (z == 1 ? O1 : O2);
    float scale = z == 0 ? QSCALE : 1.0f;
    gemm_body<true>(A, B, C, DM, DM, scale, blockIdx.x, blockIdx.y);
}

__global__ __launch_bounds__(256)
void gemm_out(const __bf16* __restrict__ A, const __bf16* __restrict__ B,
              float* __restrict__ C) {
    gemm_body<false>(A, B, C, DM, DM, 1.0f, blockIdx.x, blockIdx.y);
}

// ---------------- V transpose: Vt[h*64+d][t] = V[t][h*64+d] ----------------
__global__ __launch_bounds__(256)
void vtrans(const __bf16* __restrict__ V, __bf16* __restrict__ Vt) {
    __shared__ __bf16 tl[64][72];
    const int tid = threadIdx.x;
    const int t0  = blockIdx.x * 64;
    const int h   = blockIdx.y;
    #pragma unroll
    for (int p = 0; p < 2; ++p) {
        int c = p * 256 + tid, row = c >> 3, col8 = c & 7;
        *(bf16x8*)&tl[row][col8 * 8] =
            *(const bf16x8*)(V + (size_t)(t0 + row) * DM + h * 64 + col8 * 8);
    }
    __syncthreads();
    #pragma unroll
    for (int p = 0; p < 2; ++p) {
        int c = p * 256 + tid, d = c >> 3, tc8 = c & 7;
        bf16x8 o;
        #pragma unroll
        for (int e = 0; e < 8; ++e) o[e] = tl[tc8 * 8 + e][d];
        *(bf16x8*)(Vt + (size_t)(h * 64 + d) * T_SEQ + t0 + tc8 * 8) = o;
    }
}

// ---------------- causal flash attention v6 (kv-split) ----------------
// 2 waves/block, 64 q-rows/block. qb < SPLIT_QB: one block does the whole kv
// range and writes O. qb >= SPLIT_QB: TWO blocks each do half the kv range
// and write unnormalized U (bf16) + (m,l); attn_combine merges. This raises
// wave count 2048->3008 and halves the max per-block work (tail), attacking
// the measured occupancy/latency bound (Occ 11%, VALU 44%, Mfma 10%).
__global__ __launch_bounds__(128)
void attn_fwd(const __bf16* __restrict__ Q, const __bf16* __restrict__ Kp,
              const __bf16* __restrict__ Vt, __bf16* __restrict__ O,
              __bf16* __restrict__ U, float* __restrict__ Ml)
{
    __shared__ __align__(16) __bf16 Kl[2][64 * 64];
    __shared__ __align__(16) __bf16 Vl[2][64 * 64];
    const int tid  = threadIdx.x;
    const int lane = tid & 63, wid = tid >> 6;
    const int l31  = lane & 31;
    const int hi   = lane >> 5;
    const int h    = blockIdx.x;                 // head fastest -> XCD spread
    const int y    = blockIdx.y;                 // heavy work dispatched first
    int qb, t0i, t1i, chunk;
    bool split;
    if (y < SPLIT_QB) {                          // unsplit q-tiles, work 34..1
        qb = (SPLIT_QB - 1) - y; t0i = 0; t1i = qb; split = false; chunk = 0;
    } else {                                     // split chunks, qb 63 down
        int s = y - SPLIT_QB;
        qb = 63 - (s >> 1);
        int n = qb + 1, c0 = n - (n >> 1);
        split = true;
        if ((s & 1) == 0) { chunk = 0; t0i = 0;  t1i = c0 - 1; }
        else              { chunk = 1; t0i = c0; t1i = qb;     }
    }
    const int qw = qb * 64 + wid * 32;           // wave's first q row
    const int qg = qw + l31;                     // this lane's q row

    // Q fragments (B-operand): qf[kd0] = Q[qg][kd0*16 + hi*8 .. +7]
    bf16x8 qf[4];
    #pragma unroll
    for (int kd0 = 0; kd0 < 4; ++kd0)
        qf[kd0] = *(const bf16x8*)(Q + (size_t)qg * DM + h * 64 + kd0 * 16 + hi * 8);

    float m_i = -1e30f, l_i = 0.f;
    f32x16 oacc[2];
    #pragma unroll
    for (int d = 0; d < 2; ++d)
        #pragma unroll
        for (int e = 0; e < 16; ++e) oacc[d][e] = 0.f;

    // prologue: stage first (and second) tile via global_load_lds
    auto stage_lds = [&](int t, int buf) {
        #pragma unroll
        for (int p = 0; p < 4; ++p) {
            int u    = p * 128 + tid;          // 16B unit, 0..511
            int row  = u >> 3;
            int col8 = (u & 7) ^ (row & 7);
            gload16(Kp + (size_t)(t * 64 + row) * DM + h * 64 + col8 * 8,
                    (char*)&Kl[buf][0] + (p * 128 + wid * 64) * 16);
            gload16(Vt + (size_t)(h * 64 + row) * T_SEQ + t * 64 + col8 * 8,
                    (char*)&Vl[buf][0] + (p * 128 + wid * 64) * 16);
        }
    };
    stage_lds(t0i, 0);
    if (t1i > t0i) stage_lds(t0i + 1, 1);
    __syncthreads();

    auto qk = [&](f32x16* sdst, int buf) {
        #pragma unroll
        for (int ksub = 0; ksub < 2; ++ksub) {
            const int row = ksub * 32 + l31;
            f32x16 a;
            #pragma unroll
            for (int e = 0; e < 16; ++e) a[e] = 0.f;
            #pragma unroll
            for (int kd0 = 0; kd0 < 4; ++kd0) {
                bf16x8 kf = *(const bf16x8*)
                    &Kl[buf][(row << 6) + ((((kd0 << 1) + hi) ^ (row & 7)) << 3)];
                a = __builtin_amdgcn_mfma_f32_32x32x16_bf16(kf, qf[kd0], a, 0, 0, 0);
            }
            sdst[ksub] = a;
        }
    };
    auto mask_sf = [&](f32x16* s, int t) {
        const int kb = (t << 6) + 4 * hi;
        #pragma unroll
        for (int ksub = 0; ksub < 2; ++ksub)
            #pragma unroll
            for (int e = 0; e < 16; ++e) {
                int k = kb + ksub * 32 + ((e & 3) + 8 * (e >> 2));
                if (k > qg) s[ksub][e] = -1e30f;
            }
    };

    // sf holds S(t) at loop top
    f32x16 sf[2], sfn[2];
    qk(sf, 0);
    if (t0i == qb) mask_sf(sf, t0i);

    bf16x8 kreg[4], vreg[4];
    for (int t = t0i; t <= t1i; ++t) {
        const int cur = (t - t0i) & 1;
        const bool have_next  = (t + 1 <= t1i);
        const bool have_next2 = (t + 2 <= t1i);
        // A) issue reg-staged loads for tile t+2 (in flight across whole body)
        if (have_next2) {
            const int t2 = t + 2;
            #pragma unroll
            for (int p = 0; p < 4; ++p) {
                int u   = p * 128 + tid;
                int row = u >> 3;
                int c   = u & 7;
                kreg[p] = *(const bf16x8*)(Kp + (size_t)(t2 * 64 + row) * DM + h * 64 + c * 8);
                vreg[p] = *(const bf16x8*)(Vt + (size_t)(h * 64 + row) * T_SEQ + t2 * 64 + c * 8);
            }
        }
        // B) QK(t+1) — MFMA, independent of softmax(t)
        __builtin_amdgcn_s_setprio(1);
        if (have_next) {
            qk(sfn, cur ^ 1);
            if (t + 1 == qb) mask_sf(sfn, t + 1);
        }
        __builtin_amdgcn_s_setprio(0);
        // C) softmax(t) — VALU
        float pm;
        {
            float t0[8];
            #pragma unroll
            for (int e = 0; e < 8; ++e)
                t0[e] = fmaxf(fmaxf(sf[0][e], sf[0][e + 8]), fmaxf(sf[1][e], sf[1][e + 8]));
            #pragma unroll
            for (int s = 4; s > 0; s >>= 1)
                #pragma unroll
                for (int e = 0; e < s; ++e) t0[e] = fmaxf(t0[e], t0[e + s]);
            pm = xhalf_max(t0[0]);
        }
        if (pm > m_i + 8.f) {               // defer-max rescale
            float al = exp2f(m_i - pm);
            m_i = pm;
            l_i *= al;
            #pragma unroll
            for (int d = 0; d < 2; ++d)
                #pragma unroll
                for (int e = 0; e < 16; ++e) oacc[d][e] *= al;
        }
        float p[32];
        #pragma unroll
        for (int i = 0; i < 32; ++i)
            p[i] = exp2f(sf[i >> 4][i & 15] - m_i);
        {
            float s0[8];
            #pragma unroll
            for (int e = 0; e < 8; ++e)
                s0[e] = (p[e] + p[e + 8]) + (p[e + 16] + p[e + 24]);
            #pragma unroll
            for (int s = 4; s > 0; s >>= 1)
                #pragma unroll
                for (int e = 0; e < s; ++e) s0[e] += s0[e + s];
            l_i += xhalf_sum(s0[0]);
        }
        // D) PV(t): P->bf16 frags (cvt_pk + permlane32_swap), O^T += V^T P^T
        __builtin_amdgcn_s_setprio(1);
        #pragma unroll
        for (int ks = 0; ks < 4; ++ks) {
            unsigned w0 = cvtpk_bf16(p[8 * ks + 0], p[8 * ks + 1]);
            unsigned w1 = cvtpk_bf16(p[8 * ks + 2], p[8 * ks + 3]);
            unsigned w2 = cvtpk_bf16(p[8 * ks + 4], p[8 * ks + 5]);
            unsigned w3 = cvtpk_bf16(p[8 * ks + 6], p[8 * ks + 7]);
            permswap(w0, w2);
            permswap(w1, w3);
            union { unsigned u[4]; bf16x8 v; } pu;
            pu.u[0] = w0; pu.u[1] = w1; pu.u[2] = w2; pu.u[3] = w3;
            #pragma unroll
            for (int dsub = 0; dsub < 2; ++dsub) {
                const int row = dsub * 32 + l31;
                bf16x8 vt = *(const bf16x8*)
                    &Vl[cur][(row << 6) + ((((ks << 1) + hi) ^ (row & 7)) << 3)];
                oacc[dsub] = __builtin_amdgcn_mfma_f32_32x32x16_bf16(vt, pu.v, oacc[dsub], 0, 0, 0);
            }
        }
        __builtin_amdgcn_s_setprio(0);
        // E) commit tile t+2 into buf[cur] once all reads of buf[cur] are done
        if (have_next2) {
            __syncthreads();
            #pragma unroll
            for (int p = 0; p < 4; ++p) {
                int u   = p * 128 + tid;
                int row = u >> 3;
                int c   = u & 7;
                *(bf16x8*)&Kl[cur][(row << 6) + ((c ^ (row & 7)) << 3)] = kreg[p];
                *(bf16x8*)&Vl[cur][(row << 6) + ((c ^ (row & 7)) << 3)] = vreg[p];
            }
            __syncthreads();
        }
        if (have_next) {
            sf[0] = sfn[0];
            sf[1] = sfn[1];
        }
    }
    // ---- epilogue: transpose via per-wave LDS, store O (or U,m,l) ----
    __syncthreads();
    __bf16* ow = &Kl[0][0] + wid * 2048;   // per-wave [32 q][64 d], 16B-swizzled
    const float invl = split ? 1.0f : (1.f / l_i);
    #pragma unroll
    for (int dsub = 0; dsub < 2; ++dsub)
        #pragma unroll
        for (int e = 0; e < 16; ++e) {
            int d = dsub * 32 + ((e & 3) + 8 * (e >> 2)) + 4 * hi;
            float v = oacc[dsub][e] * invl;
            int bo = l31 * 128 + ((2 * d) ^ ((l31 & 7) << 4));
            *(__bf16*)((char*)ow + bo) = (__bf16)v;
        }
    if (!split) {
        #pragma unroll
        for (int i = 0; i < 4; ++i) {
            int u  = hi * 4 + i;
            int bo = l31 * 128 + ((u * 16) ^ ((l31 & 7) << 4));
            bf16x8 v8 = *(const bf16x8*)((char*)ow + bo);
            *(bf16x8*)(O + (size_t)qg * DM + h * 64 + u * 8) = v8;
        }
    } else {
        const int ridx = qg - SPLIT_QB * 64;
        #pragma unroll
        for (int i = 0; i < 4; ++i) {
            int u  = hi * 4 + i;
            int bo = l31 * 128 + ((u * 16) ^ ((l31 & 7) << 4));
            bf16x8 v8 = *(const bf16x8*)((char*)ow + bo);
            *(bf16x8*)(U + ((size_t)(chunk * NH + h) * SPLIT_ROWS + ridx) * 64 + u * 8) = v8;
        }
        if (hi == 0) {
            float* mlp = Ml + ((size_t)(chunk * NH + h) * SPLIT_ROWS + ridx) * 2;
            mlp[0] = m_i;
            mlp[1] = l_i;
        }
    }
}

// ---------------- combine the two kv-chunks for split rows ----------------
// one 8-thread group per (row, head): O = (U0*2^(m0-M) + U1*2^(m1-M)) / denom
__global__ __launch_bounds__(256)
void attn_combine(const __bf16* __restrict__ U, const float* __restrict__ Ml,
                  __bf16* __restrict__ O) {
    int gid = blockIdx.x * 256 + threadIdx.x;    // 0 .. SPLIT_ROWS*NH*8-1
    int rh  = gid >> 3;
    int e8  = gid & 7;
    int ridx = rh >> 4, h = rh & 15;
    const float* ml0 = Ml + ((size_t)(0 * NH + h) * SPLIT_ROWS + ridx) * 2;
    const float* ml1 = Ml + ((size_t)(1 * NH + h) * SPLIT_ROWS + ridx) * 2;
    float m0 = ml0[0], l0 = ml0[1], m1 = ml1[0], l1 = ml1[1];
    float M  = fmaxf(m0, m1);
    float s0 = exp2f(m0 - M), s1 = exp2f(m1 - M);
    float inv = 1.f / (l0 * s0 + l1 * s1);
    bf16x8 u0 = *(const bf16x8*)(U + ((size_t)(0 * NH + h) * SPLIT_ROWS + ridx) * 64 + e8 * 8);
    bf16x8 u1 = *(const bf16x8*)(U + ((size_t)(1 * NH + h) * SPLIT_ROWS + ridx) * 64 + e8 * 8);
    bf16x8 o;
    #pragma unroll
    for (int j = 0; j < 8; ++j)
        o[j] = (__bf16)(((float)u0[j] * s0 + (float)u1[j] * s1) * inv);
    *(bf16x8*)(O + (size_t)(SPLIT_QB * 64 + ridx) * DM + h * 64 + e8 * 8) = o;
}

extern "C" void kernel_launch(void* const* d_in, const int* in_sizes, int n_in,
                              void* d_out, int out_size, void* d_ws, size_t ws_size,
                              hipStream_t stream) {
    const float* x  = (const float*)d_in[0];
    const float* Wq = (const float*)d_in[1];
    const float* Wk = (const float*)d_in[2];
    const float* Wv = (const float*)d_in[3];
    const float* Wo = (const float*)d_in[4];
    float* out = (float*)d_out;

    char* ws = (char*)d_ws;
    const size_t MB = (size_t)1 << 20;
    __bf16* xb    = (__bf16*)(ws + 0 * MB);    // 8 MiB (dead after QKV gemms)
    __bf16* VtG   = (__bf16*)(ws + 0 * MB);    // reuses xb region
    __bf16* wqb   = (__bf16*)(ws + 8 * MB);
    float*  MlB   = (float*)(ws + 8 * MB);     // reuses wqb (dead after qkv): 0.5 MiB
    __bf16* wkb   = (__bf16*)(ws + 10 * MB);
    __bf16* wvb   = (__bf16*)(ws + 12 * MB);
    __bf16* wob   = (__bf16*)(ws + 14 * MB);
    __bf16* Qb    = (__bf16*)(ws + 16 * MB);
    __bf16* Kb    = (__bf16*)(ws + 24 * MB);
    __bf16* Vb    = (__bf16*)(ws + 32 * MB);
    __bf16* UB    = (__bf16*)(ws + 32 * MB);   // reuses Vb (dead after vtrans): 7.9 MiB
    __bf16* attnb = (__bf16*)(ws + 40 * MB);   // ends at 48 MiB

    const int nX = T_SEQ * DM / 4;
    const int nW = DM * DM / 4;
    cvt_bf16<<<(nX + 255) / 256, 256, 0, stream>>>(x, xb, nX);
    cvt4_bf16<<<dim3((nW + 255) / 256, 4), 256, 0, stream>>>(Wq, Wk, Wv, Wo,
                                                             wqb, wkb, wvb, wob, nW);

    gemm_qkv<<<dim3(DM / 128, T_SEQ / 128, 3), 256, 0, stream>>>(xb, wqb, wkb, wvb, Qb, Kb, Vb);

    vtrans<<<dim3(T_SEQ / 64, NH), 256, 0, stream>>>(Vb, VtG);

    // y: 0..33 unsplit (qb=33..0), 34..93 split chunks (qb=63..34, 2 each)
    attn_fwd<<<dim3(NH, SPLIT_QB + 2 * (64 - SPLIT_QB)), 128, 0, stream>>>(
        Qb, Kb, VtG, attnb, UB, MlB);

    attn_combine<<<(SPLIT_ROWS * NH * 8) / 256, 256, 0, stream>>>(UB, MlB, attnb);

    gemm_out<<<dim3(DM / 128, T_SEQ / 128), 256, 0, stream>>>(attnb, wob, out);
}